// Round 5
// baseline (829.023 us; speedup 1.0000x reference)
//
#include <hip/hip_runtime.h>
#include <hip/hip_bf16.h>
#include <math.h>

typedef float f32x4 __attribute__((ext_vector_type(4)));
typedef float f32x2 __attribute__((ext_vector_type(2)));
typedef short s16x8 __attribute__((ext_vector_type(8)));
typedef short s16x4 __attribute__((ext_vector_type(4)));
typedef int   i32x4 __attribute__((ext_vector_type(4)));

__device__ __forceinline__ short f2bf(float f) {
  __hip_bfloat16 h = __float2bfloat16(f);
  return __builtin_bit_cast(short, h);
}
__device__ __forceinline__ float bf2f(short s) {
  __hip_bfloat16 h = __builtin_bit_cast(__hip_bfloat16, s);
  return __bfloat162float(h);
}
__device__ __forceinline__ float gelu_f(float x) {
  return 0.5f * x * (1.f + erff(x * 0.70710678118654752440f));
}
__device__ __forceinline__ float waveSum(float v) {
  #pragma unroll
  for (int d = 32; d; d >>= 1) v += __shfl_xor(v, d);
  return v;
}

// ---------------------------------------------------------------------------
// K1: dual LayerNorm over D=128 (qkv_ln and pin_ln) -> bf16 A-matrices
// ---------------------------------------------------------------------------
__global__ __launch_bounds__(256) void ln_dual_k(
    const float* __restrict__ x,
    const float* __restrict__ qg, const float* __restrict__ qb,
    const float* __restrict__ pg, const float* __restrict__ pb,
    short* __restrict__ lnq, short* __restrict__ lnp)
{
  int w = threadIdx.x >> 6, lane = threadIdx.x & 63;
  size_t row = (size_t)blockIdx.x * 4 + w;
  f32x2 v = reinterpret_cast<const f32x2*>(x + row * 128)[lane];
  float s  = v[0] + v[1];
  float sq = v[0]*v[0] + v[1]*v[1];
  s = waveSum(s); sq = waveSum(sq);
  float m = s * (1.f/128.f);
  float rstd = rsqrtf(sq * (1.f/128.f) - m*m + 1e-5f);
  int c = lane * 2;
  float a0 = (v[0]-m)*rstd, a1 = (v[1]-m)*rstd;
  unsigned q0 = (unsigned short)f2bf(a0*qg[c] + qb[c]);
  unsigned q1 = (unsigned short)f2bf(a1*qg[c+1] + qb[c+1]);
  unsigned p0 = (unsigned short)f2bf(a0*pg[c] + pb[c]);
  unsigned p1 = (unsigned short)f2bf(a1*pg[c+1] + pb[c+1]);
  ((unsigned*)lnq)[row*64 + lane] = q0 | (q1 << 16);
  ((unsigned*)lnp)[row*64 + lane] = p0 | (p1 << 16);
}

// ---------------------------------------------------------------------------
// K2: LayerNorm over 256 (attn_ln), fp32 in/out
// ---------------------------------------------------------------------------
__global__ __launch_bounds__(256) void ln256_k(
    const float* __restrict__ in,
    const float* __restrict__ g, const float* __restrict__ bb,
    float* __restrict__ out)
{
  int w = threadIdx.x >> 6, lane = threadIdx.x & 63;
  size_t row = (size_t)blockIdx.x * 4 + w;
  f32x4 v = reinterpret_cast<const f32x4*>(in + row * 256)[lane];
  float s  = v[0]+v[1]+v[2]+v[3];
  float sq = v[0]*v[0]+v[1]*v[1]+v[2]*v[2]+v[3]*v[3];
  s = waveSum(s); sq = waveSum(sq);
  float m = s * (1.f/256.f);
  float rstd = rsqrtf(sq * (1.f/256.f) - m*m + 1e-5f);
  f32x4 g4 = reinterpret_cast<const f32x4*>(g)[lane];
  f32x4 b4 = reinterpret_cast<const f32x4*>(bb)[lane];
  f32x4 o;
  #pragma unroll
  for (int k = 0; k < 4; ++k) o[k] = (v[k]-m)*rstd*g4[k] + b4[k];
  reinterpret_cast<f32x4*>(out + row * 256)[lane] = o;
}

// ---------------------------------------------------------------------------
// K3: LayerNorm over 8192 (mlp_ln) -> bf16
// ---------------------------------------------------------------------------
__global__ __launch_bounds__(256) void ln8192_k(
    const float* __restrict__ x1,
    const float* __restrict__ g, const float* __restrict__ bb,
    short* __restrict__ lnx)
{
  __shared__ float red[8];
  int t = threadIdx.x, w = t >> 6, lane = t & 63;
  int b = blockIdx.x;
  const f32x4* xr = reinterpret_cast<const f32x4*>(x1 + (size_t)b * 8192);
  f32x4 vals[8];
  float s = 0.f, sq = 0.f;
  #pragma unroll
  for (int i = 0; i < 8; ++i) {
    f32x4 v = xr[t + i*256];
    vals[i] = v;
    s  += v[0]+v[1]+v[2]+v[3];
    sq += v[0]*v[0]+v[1]*v[1]+v[2]*v[2]+v[3]*v[3];
  }
  s = waveSum(s); sq = waveSum(sq);
  if (lane == 0) { red[w] = s; red[4+w] = sq; }
  __syncthreads();
  s  = red[0]+red[1]+red[2]+red[3];
  sq = red[4]+red[5]+red[6]+red[7];
  float m = s * (1.f/8192.f);
  float rstd = rsqrtf(sq * (1.f/8192.f) - m*m + 1e-5f);
  #pragma unroll
  for (int i = 0; i < 8; ++i) {
    int idx = (t + i*256) * 4;
    f32x4 g4 = reinterpret_cast<const f32x4*>(g)[t + i*256];
    f32x4 b4 = reinterpret_cast<const f32x4*>(bb)[t + i*256];
    s16x4 o;
    #pragma unroll
    for (int k = 0; k < 4; ++k) o[k] = f2bf((vals[i][k]-m)*rstd*g4[k] + b4[k]);
    *reinterpret_cast<s16x4*>(&lnx[(size_t)b*8192 + idx]) = o;
  }
}

// ---------------------------------------------------------------------------
// Generic bf16-MFMA GEMM for the small GEMMs.
// EPI: 0 = bf16 out (+bias); 1 = f32 out (+bias); 2 = gelu split u/v (pin);
//      3 = f32 out (+bias +res)
// ---------------------------------------------------------------------------
template<int BM, int BN, int WM, int WN, int EPI>
__global__ __launch_bounds__(256) void gemm_k(
    const short* __restrict__ A, const float* __restrict__ Bw,
    const float* __restrict__ bias, const float* __restrict__ res,
    void* __restrict__ O0, void* __restrict__ O1,
    int M, int N, int K, int Nreal, int Kreal)
{
  constexpr int BK = 64;
  __shared__ __align__(16) short As[BM][BK + 8];
  __shared__ __align__(16) short Bs[BN][BK + 8];
  const int t = threadIdx.x;
  const int lane = t & 63;
  const int w = t >> 6;
  const int wm = w / WN, wn = w % WN;
  const int ln15 = lane & 15, hi = lane >> 4;
  const int m0 = blockIdx.y * BM;
  const int n0 = blockIdx.x * BN;

  f32x4 acc[4][4] = {};

  for (int k0 = 0; k0 < K; k0 += BK) {
    #pragma unroll
    for (int i = 0; i < (BM*BK)/(256*8); ++i) {
      int e = (i*256 + t) * 8;
      int r = e / BK, c = e % BK;
      *reinterpret_cast<i32x4*>(&As[r][c]) =
          *reinterpret_cast<const i32x4*>(&A[(size_t)(m0 + r) * K + k0 + c]);
    }
    #pragma unroll
    for (int i = 0; i < (BK*BN)/256; ++i) {
      int idx = i*256 + t;
      int n = idx % BN, k = idx / BN;
      int gk = k0 + k, gn = n0 + n;
      float v = (gk < Kreal && gn < Nreal) ? Bw[(size_t)gk * Nreal + gn] : 0.f;
      Bs[n][k] = f2bf(v);
    }
    __syncthreads();
    #pragma unroll
    for (int kk = 0; kk < BK; kk += 32) {
      s16x8 af[4], bfr[4];
      #pragma unroll
      for (int fm = 0; fm < 4; ++fm)
        af[fm] = *reinterpret_cast<const s16x8*>(&As[wm*64 + fm*16 + ln15][kk + hi*8]);
      #pragma unroll
      for (int fn = 0; fn < 4; ++fn)
        bfr[fn] = *reinterpret_cast<const s16x8*>(&Bs[wn*64 + fn*16 + ln15][kk + hi*8]);
      #pragma unroll
      for (int fm = 0; fm < 4; ++fm)
        #pragma unroll
        for (int fn = 0; fn < 4; ++fn)
          acc[fm][fn] = __builtin_amdgcn_mfma_f32_16x16x32_bf16(
              af[fm], bfr[fn], acc[fm][fn], 0, 0, 0);
    }
    __syncthreads();
  }

  #pragma unroll
  for (int fm = 0; fm < 4; ++fm) {
    #pragma unroll
    for (int fn = 0; fn < 4; ++fn) {
      #pragma unroll
      for (int j = 0; j < 4; ++j) {
        int row = m0 + wm*64 + fm*16 + hi*4 + j;
        int col = n0 + wn*64 + fn*16 + ln15;
        float v = acc[fm][fn][j];
        if constexpr (EPI == 0) {
          v += bias[col];
          ((short*)O0)[(size_t)row * N + col] = f2bf(v);
        } else if constexpr (EPI == 1) {
          v += bias[col];
          ((float*)O0)[(size_t)row * N + col] = v;
        } else if constexpr (EPI == 2) {
          v = gelu_f(v + bias[col]);
          if (col < 256) ((float*)O0)[(size_t)row * 256 + col] = v;
          else ((short*)O1)[(size_t)row * 256 + (col - 256)] = f2bf(v);
        } else { // 3
          v += bias[col] + res[(size_t)row * N + col];
          ((float*)O0)[(size_t)row * N + col] = v;
        }
      }
    }
  }
}

// ---------------------------------------------------------------------------
// Split-K GEMM v4 for the fat MLP GEMMs.
// BM=512 (all of M), BN=128, BK=64. 512 threads / 8 waves; wave w owns rows
// [64w,64w+64) x all 128 cols: acc[4][8].
// XCD-aware mapping: xcd = bid&7 (HW round-robin), slot = bid>>3.
//   z  = xcd >> 1          (all blocks on an XCD share the k-split!)
//   nt = (xcd & 1) * slots + slot
// => per-XCD A working set = one 2.1-2.3 MB k-chunk, stays L2-resident;
//    A re-reads come from XCD-L2 (~4.3 TB/s/XCD) instead of the LLC.
// B loads issued FIRST (HBM, long latency), then A (L2-hit).
// Single-buffered LDS, prefetch distance 1. A: XOR-granule swizzle; B: +8 pad.
// ---------------------------------------------------------------------------
__global__ __launch_bounds__(512, 2) void gemm_splitk4(
    const short* __restrict__ A, const float* __restrict__ Bw,
    float* __restrict__ part,
    int N, int K, int Kreal, int ldb, int kchunk, int ntiles, int slots)
{
  __shared__ __align__(16) short As[512 * 64];   // 64 KB
  __shared__ __align__(16) short Bs[128 * 72];   // 18 KB (+8 pad per row)
  const int t = threadIdx.x, lane = t & 63, w = t >> 6;
  const int ln15 = lane & 15, hi = lane >> 4;

  const int xcd = blockIdx.x & 7, slot = blockIdx.x >> 3;
  const int z = xcd >> 1;
  const int nt = (xcd & 1) * slots + slot;
  if (nt >= ntiles) return;
  const int n0 = nt * 128;
  const int kbeg = z * kchunk;
  const int kend = (kbeg + kchunk < K) ? (kbeg + kchunk) : K;
  const int nsteps = (kend - kbeg) >> 6;

  // A staging: thread handles granule (t&7) of rows (t>>3)+64i
  const int arow = t >> 3, ag = t & 7;
  const int agsw = ag ^ (arow & 7);
  // B staging: thread handles col (t&127), k-run [(t>>7)*16, +16)
  const int bn = t & 127;
  const int bk0 = (t >> 7) * 16;
  const bool bcol_ok = (n0 + bn) < ldb;

  i32x4 ar[8];
  float br[16];

  auto loadAB = [&](int k0) {
    // B first: HBM latency starts draining earliest
    const float* bp = Bw + (size_t)(k0 + bk0) * ldb + n0 + bn;
    #pragma unroll
    for (int m = 0; m < 16; ++m) {
      int gk = k0 + bk0 + m;
      br[m] = (bcol_ok && gk < Kreal) ? bp[(size_t)m * ldb] : 0.f;
    }
    #pragma unroll
    for (int i = 0; i < 8; ++i)
      ar[i] = *reinterpret_cast<const i32x4*>(
          &A[(size_t)(arow + 64 * i) * K + k0 + ag * 8]);
  };
  auto writeAB = [&]() {
    #pragma unroll
    for (int i = 0; i < 8; ++i) {
      int rr = arow + 64 * i;
      *reinterpret_cast<i32x4*>(&As[rr * 64 + agsw * 8]) = ar[i];
    }
    s16x8 v0, v1;
    #pragma unroll
    for (int m = 0; m < 8; ++m) { v0[m] = f2bf(br[m]); v1[m] = f2bf(br[8 + m]); }
    *reinterpret_cast<s16x8*>(&Bs[bn * 72 + bk0]) = v0;
    *reinterpret_cast<s16x8*>(&Bs[bn * 72 + bk0 + 8]) = v1;
  };

  f32x4 acc[4][8] = {};

  loadAB(kbeg);
  writeAB();
  __syncthreads();

  for (int s = 0; s < nsteps; ++s) {
    if (s + 1 < nsteps) loadAB(kbeg + (s + 1) * 64);   // prefetch before compute
    #pragma unroll
    for (int kk = 0; kk < 2; ++kk) {
      int g = kk * 4 + hi;
      s16x8 af[4];
      #pragma unroll
      for (int fm = 0; fm < 4; ++fm) {
        int row = w * 64 + fm * 16 + ln15;
        af[fm] = *reinterpret_cast<const s16x8*>(&As[row * 64 + ((g ^ (row & 7)) * 8)]);
      }
      #pragma unroll
      for (int fn = 0; fn < 8; ++fn) {
        s16x8 bv = *reinterpret_cast<const s16x8*>(&Bs[(fn * 16 + ln15) * 72 + g * 8]);
        #pragma unroll
        for (int fm = 0; fm < 4; ++fm)
          acc[fm][fn] = __builtin_amdgcn_mfma_f32_16x16x32_bf16(
              af[fm], bv, acc[fm][fn], 0, 0, 0);
      }
    }
    __syncthreads();
    if (s + 1 < nsteps) { writeAB(); __syncthreads(); }
  }

  #pragma unroll
  for (int fm = 0; fm < 4; ++fm)
    #pragma unroll
    for (int fn = 0; fn < 8; ++fn)
      #pragma unroll
      for (int j = 0; j < 4; ++j) {
        int row = w * 64 + fm * 16 + hi * 4 + j;
        int col = n0 + fn * 16 + ln15;
        part[((size_t)z * 512 + row) * N + col] = acc[fm][fn][j];
      }
}

// ---------------------------------------------------------------------------
// split-K reduce for mlp1: h3 = gelu(sum_ks part + b1), bf16, col<Nreal guard
// ---------------------------------------------------------------------------
__global__ __launch_bounds__(256) void reduce_mlp1_k(
    const float* __restrict__ part, const float* __restrict__ bias,
    short* __restrict__ h3, int N, int Nreal, int M)
{
  int col4 = (blockIdx.x * 256 + threadIdx.x) * 4;
  int row = blockIdx.y;
  if (col4 >= N) return;
  size_t base = (size_t)row * N + col4;
  size_t stride = (size_t)M * N;
  f32x4 s = *reinterpret_cast<const f32x4*>(part + base);
  #pragma unroll
  for (int ks = 1; ks < 4; ++ks)
    s += *reinterpret_cast<const f32x4*>(part + base + (size_t)ks * stride);
  s16x4 o;
  #pragma unroll
  for (int j = 0; j < 4; ++j) {
    int c = col4 + j;
    float v = 0.f;
    if (c < Nreal) v = gelu_f(s[j] + bias[c]);
    o[j] = f2bf(v);
  }
  *reinterpret_cast<s16x4*>(h3 + base) = o;
}

// ---------------------------------------------------------------------------
// split-K reduce for mlp2: out = sum_ks part + b2 + x1 (f32)
// ---------------------------------------------------------------------------
__global__ __launch_bounds__(256) void reduce_mlp2_k(
    const float* __restrict__ part, const float* __restrict__ bias,
    const float* __restrict__ x1, float* __restrict__ out, int N, int M)
{
  int col4 = (blockIdx.x * 256 + threadIdx.x) * 4;
  int row = blockIdx.y;
  size_t base = (size_t)row * N + col4;
  size_t stride = (size_t)M * N;
  f32x4 s = *reinterpret_cast<const f32x4*>(part + base);
  #pragma unroll
  for (int ks = 1; ks < 4; ++ks)
    s += *reinterpret_cast<const f32x4*>(part + base + (size_t)ks * stride);
  f32x4 b4 = *reinterpret_cast<const f32x4*>(bias + col4);
  f32x4 r4 = *reinterpret_cast<const f32x4*>(x1 + base);
  #pragma unroll
  for (int j = 0; j < 4; ++j) s[j] += b4[j] + r4[j];
  *reinterpret_cast<f32x4*>(out + base) = s;
}

// ---------------------------------------------------------------------------
// K4: fused tiny attention
// ---------------------------------------------------------------------------
__global__ __launch_bounds__(256) void attn_k(
    const short* __restrict__ qkv, const float* __restrict__ relb,
    const float* __restrict__ scale_p, short* __restrict__ av)
{
  __shared__ __align__(16) short qlds[64][136];
  __shared__ __align__(16) short klds[64][136];
  __shared__ __align__(16) short plds[64][72];
  __shared__ __align__(16) short vlds[128][72];
  __shared__ float rb[127];
  int t = threadIdx.x, lane = t & 63, w = t >> 6;
  int ln15 = lane & 15, hi = lane >> 4;
  int b = blockIdx.x;
  if (t < 127) rb[t] = relb[t];

  f32x4 sacc[4] = {};
  for (int kc = 0; kc < 4; ++kc) {
    #pragma unroll
    for (int i = 0; i < 4; ++i) {
      int e = (i*256 + t) * 8;
      int r = e >> 7, c = e & 127;
      size_t base = (size_t)(b*64 + r) * 1536 + kc*128 + c;
      *reinterpret_cast<i32x4*>(&qlds[r][c]) = *reinterpret_cast<const i32x4*>(&qkv[base]);
      *reinterpret_cast<i32x4*>(&klds[r][c]) = *reinterpret_cast<const i32x4*>(&qkv[base + 512]);
    }
    __syncthreads();
    #pragma unroll
    for (int kk = 0; kk < 128; kk += 32) {
      s16x8 aq = *reinterpret_cast<const s16x8*>(&qlds[16*w + ln15][kk + hi*8]);
      #pragma unroll
      for (int fn = 0; fn < 4; ++fn) {
        s16x8 bk = *reinterpret_cast<const s16x8*>(&klds[fn*16 + ln15][kk + hi*8]);
        sacc[fn] = __builtin_amdgcn_mfma_f32_16x16x32_bf16(aq, bk, sacc[fn], 0, 0, 0);
      }
    }
    __syncthreads();
  }

  float scale = scale_p[0];
  #pragma unroll
  for (int j = 0; j < 4; ++j) {
    int row = 16*w + hi*4 + j;
    float pv[4];
    float mx = -1e30f;
    #pragma unroll
    for (int fn = 0; fn < 4; ++fn) {
      int col = fn*16 + ln15;
      pv[fn] = sacc[fn][j] + rb[col - row + 63];
      mx = fmaxf(mx, pv[fn]);
    }
    #pragma unroll
    for (int d = 1; d < 16; d <<= 1) mx = fmaxf(mx, __shfl_xor(mx, d));
    float sum = 0.f;
    #pragma unroll
    for (int fn = 0; fn < 4; ++fn) { pv[fn] = __expf(pv[fn] - mx); sum += pv[fn]; }
    #pragma unroll
    for (int d = 1; d < 16; d <<= 1) sum += __shfl_xor(sum, d);
    float inv = scale / sum;
    #pragma unroll
    for (int fn = 0; fn < 4; ++fn) plds[row][fn*16 + ln15] = f2bf(pv[fn] * inv);
  }
  __syncthreads();

  for (int cc = 0; cc < 4; ++cc) {
    #pragma unroll
    for (int i = 0; i < 8; ++i) {
      int idx = i*256 + t;
      int s = idx >> 5, c4 = (idx & 31) * 4;
      s16x4 vw = *reinterpret_cast<const s16x4*>(
          &qkv[(size_t)(b*64 + s) * 1536 + 1024 + cc*128 + c4]);
      vlds[c4+0][s] = vw[0]; vlds[c4+1][s] = vw[1];
      vlds[c4+2][s] = vw[2]; vlds[c4+3][s] = vw[3];
    }
    __syncthreads();
    f32x4 pacc[8] = {};
    #pragma unroll
    for (int kk = 0; kk < 64; kk += 32) {
      s16x8 ap = *reinterpret_cast<const s16x8*>(&plds[16*w + ln15][kk + hi*8]);
      #pragma unroll
      for (int fn = 0; fn < 8; ++fn) {
        s16x8 bv = *reinterpret_cast<const s16x8*>(&vlds[fn*16 + ln15][kk + hi*8]);
        pacc[fn] = __builtin_amdgcn_mfma_f32_16x16x32_bf16(ap, bv, pacc[fn], 0, 0, 0);
      }
    }
    #pragma unroll
    for (int fn = 0; fn < 8; ++fn)
      #pragma unroll
      for (int j = 0; j < 4; ++j) {
        int row = b*64 + 16*w + hi*4 + j;
        int col = cc*128 + fn*16 + ln15;
        av[(size_t)row * 512 + col] = f2bf(pacc[fn][j]);
      }
    __syncthreads();
  }
}

// ---------------------------------------------------------------------------
// K5: SGU gate
// ---------------------------------------------------------------------------
__global__ __launch_bounds__(256) void gate_k(
    const float* __restrict__ u, const short* __restrict__ vbf,
    const float* __restrict__ a,
    const float* __restrict__ spg_g, const float* __restrict__ spg_b,
    const float* __restrict__ spw, const float* __restrict__ spb,
    const float* __restrict__ pog, const float* __restrict__ pob,
    short* __restrict__ outn)
{
  __shared__ __align__(16) short nvb[256][72];
  __shared__ __align__(16) short spwT[64][72];
  __shared__ float s_spg[64], s_spbl[64], s_spb[64];
  __shared__ float s_pog[256], s_pob[256];
  int t = threadIdx.x, lane = t & 63, w = t >> 6;
  int ln15 = lane & 15, hi = lane >> 4;
  int b = blockIdx.x;

  if (t < 64) { s_spg[t] = spg_g[t]; s_spbl[t] = spg_b[t]; s_spb[t] = spb[t]; }
  s_pog[t] = pog[t]; s_pob[t] = pob[t];
  #pragma unroll
  for (int i = 0; i < 16; ++i) {
    int idx = i*256 + t;
    int sr = idx >> 6, tc = idx & 63;
    spwT[tc][sr] = f2bf(spw[idx]);
  }

  float vvv[64];
  {
    int c = t;
    float s = 0.f, sq = 0.f;
    #pragma unroll
    for (int si = 0; si < 64; ++si) {
      float f = bf2f(vbf[(size_t)(b*64 + si) * 256 + c]);
      vvv[si] = f; s += f; sq += f*f;
    }
    float m = s * (1.f/64.f);
    float rstd = rsqrtf(sq * (1.f/64.f) - m*m + 1e-5f);
    __syncthreads();
    #pragma unroll
    for (int si = 0; si < 64; ++si)
      nvb[c][si] = f2bf((vvv[si]-m)*rstd*s_spg[si] + s_spbl[si]);
  }
  __syncthreads();

  f32x4 yacc[4][4] = {};
  #pragma unroll
  for (int kk = 0; kk < 64; kk += 32) {
    s16x8 af[4], bfr[4];
    #pragma unroll
    for (int fm = 0; fm < 4; ++fm)
      af[fm] = *reinterpret_cast<const s16x8*>(&nvb[64*w + fm*16 + ln15][kk + hi*8]);
    #pragma unroll
    for (int fn = 0; fn < 4; ++fn)
      bfr[fn] = *reinterpret_cast<const s16x8*>(&spwT[fn*16 + ln15][kk + hi*8]);
    #pragma unroll
    for (int fm = 0; fm < 4; ++fm)
      #pragma unroll
      for (int fn = 0; fn < 4; ++fn)
        yacc[fm][fn] = __builtin_amdgcn_mfma_f32_16x16x32_bf16(
            af[fm], bfr[fn], yacc[fm][fn], 0, 0, 0);
  }
  __syncthreads();

  short (*outl)[264] = reinterpret_cast<short(*)[264]>(&nvb[0][0]);
  #pragma unroll
  for (int fm = 0; fm < 4; ++fm) {
    #pragma unroll
    for (int fn = 0; fn < 4; ++fn) {
      int crow = 64*w + fm*16 + hi*4;
      int tcol = fn*16 + ln15;
      f32x4 u4 = *reinterpret_cast<const f32x4*>(&u[(size_t)(b*64 + tcol)*256 + crow]);
      f32x4 a4 = *reinterpret_cast<const f32x4*>(&a[(size_t)(b*64 + tcol)*256 + crow]);
      #pragma unroll
      for (int j = 0; j < 4; ++j) {
        float g = gelu_f(yacc[fm][fn][j] + s_spb[tcol]);
        float o = u4[j] * (g + a4[j]);
        outl[tcol][crow + j] = f2bf(o);
      }
    }
  }
  __syncthreads();

  #pragma unroll
  for (int ri = 0; ri < 16; ++ri) {
    int trow = w*16 + ri;
    int c = lane * 4;
    s16x4 raw = *reinterpret_cast<const s16x4*>(&outl[trow][c]);
    float f0 = bf2f(raw[0]), f1 = bf2f(raw[1]), f2 = bf2f(raw[2]), f3 = bf2f(raw[3]);
    float s  = f0+f1+f2+f3;
    float sq = f0*f0+f1*f1+f2*f2+f3*f3;
    s = waveSum(s); sq = waveSum(sq);
    float m = s * (1.f/256.f);
    float rstd = rsqrtf(sq * (1.f/256.f) - m*m + 1e-5f);
    s16x4 o;
    o[0] = f2bf((f0-m)*rstd*s_pog[c+0] + s_pob[c+0]);
    o[1] = f2bf((f1-m)*rstd*s_pog[c+1] + s_pob[c+1]);
    o[2] = f2bf((f2-m)*rstd*s_pog[c+2] + s_pob[c+2]);
    o[3] = f2bf((f3-m)*rstd*s_pog[c+3] + s_pob[c+3]);
    *reinterpret_cast<s16x4*>(&outn[(size_t)(b*64 + trow)*256 + c]) = o;
  }
}

// ---------------------------------------------------------------------------
extern "C" void kernel_launch(void* const* d_in, const int* in_sizes, int n_in,
                              void* d_out, int out_size, void* d_ws, size_t ws_size,
                              hipStream_t stream)
{
  const float* x          = (const float*)d_in[0];
  const float* qkv_ln_g   = (const float*)d_in[1];
  const float* qkv_ln_b   = (const float*)d_in[2];
  const float* qkv_w      = (const float*)d_in[3];
  const float* qkv_b      = (const float*)d_in[4];
  const float* attn_pw    = (const float*)d_in[5];
  const float* attn_pb    = (const float*)d_in[6];
  const float* attn_ln_g  = (const float*)d_in[7];
  const float* attn_ln_b  = (const float*)d_in[8];
  const float* rel_bias   = (const float*)d_in[9];
  const float* scale      = (const float*)d_in[10];
  const float* pin_ln_g   = (const float*)d_in[11];
  const float* pin_ln_b   = (const float*)d_in[12];
  const float* pin_w      = (const float*)d_in[13];
  const float* pin_b      = (const float*)d_in[14];
  const float* sp_ln_g    = (const float*)d_in[15];
  const float* sp_ln_b    = (const float*)d_in[16];
  const float* sp_w       = (const float*)d_in[17];
  const float* sp_b       = (const float*)d_in[18];
  const float* pout_ln_g  = (const float*)d_in[19];
  const float* pout_ln_b  = (const float*)d_in[20];
  const float* pout_w     = (const float*)d_in[21];
  const float* pout_b     = (const float*)d_in[22];
  const float* mlp_ln_g   = (const float*)d_in[23];
  const float* mlp_ln_b   = (const float*)d_in[24];
  const float* mlp_w1     = (const float*)d_in[25];
  const float* mlp_b1     = (const float*)d_in[26];
  const float* mlp_w2     = (const float*)d_in[27];
  const float* mlp_b2     = (const float*)d_in[28];

  char* ws = (char*)d_ws;
  short* lnq  = (short*)(ws + 0);            // 8.39 MB
  short* lnp  = (short*)(ws + 8388608);      // 8.39 MB
  short* qkvb = (short*)(ws + 16777216);     // 100.7 MB (dead after attn)
  short* avb  = (short*)(ws + 117440512);    // 33.6 MB
  float* projb= (float*)(ws + 16777216);     // alias qkv region
  float* ab   = (float*)(ws + 50331648);     // alias qkv region
  float* ub   = (float*)(ws + 83886080);     // alias qkv region
  short* vbfb = (short*)(ws + 117440512);    // alias av region
  short* outnb= (short*)(ws + 134217728);    // alias av region
  float* x1b  = (float*)(ws + 0);            // alias lnq/lnp region [0,16.8MB)
  short* lnxb = (short*)(ws + 150994944);    // 8.39 MB
  short* h3b  = (short*)(ws + 159383552);    // 9.31 MB (512 x 9088, pad zeroed)
  float* partb= (float*)(ws + 16777216);     // split-K partials (<=74.5 MB)

  ln_dual_k<<<8192, 256, 0, stream>>>(x, qkv_ln_g, qkv_ln_b, pin_ln_g, pin_ln_b, lnq, lnp);
  gemm_k<128,128,2,2,0><<<dim3(12,256), 256, 0, stream>>>(
      lnq, qkv_w, qkv_b, nullptr, qkvb, nullptr, 32768, 1536, 128, 1536, 128);
  attn_k<<<512, 256, 0, stream>>>(qkvb, rel_bias, scale, avb);
  gemm_k<128,128,2,2,1><<<dim3(2,256), 256, 0, stream>>>(
      avb, attn_pw, attn_pb, nullptr, projb, nullptr, 32768, 256, 512, 256, 512);
  ln256_k<<<8192, 256, 0, stream>>>(projb, attn_ln_g, attn_ln_b, ab);
  gemm_k<128,128,2,2,2><<<dim3(4,256), 256, 0, stream>>>(
      lnp, pin_w, pin_b, nullptr, ub, vbfb, 32768, 512, 128, 512, 128);
  gate_k<<<512, 256, 0, stream>>>(ub, vbfb, ab, sp_ln_g, sp_ln_b, sp_w, sp_b,
                                  pout_ln_g, pout_ln_b, outnb);
  gemm_k<128,128,2,2,3><<<dim3(1,256), 256, 0, stream>>>(
      outnb, pout_w, pout_b, x, x1b, nullptr, 32768, 128, 256, 128, 256);
  ln8192_k<<<512, 256, 0, stream>>>(x1b, mlp_ln_g, mlp_ln_b, lnxb);

  // mlp1: [512,8192] @ [8192,9011] (N padded 9088 = 71*128), split-K 4.
  // XCD-mapped grid: 8 xcd * 36 slots = 288 blocks (odd xcd, slot 35 idle).
  gemm_splitk4<<<288, 512, 0, stream>>>(
      lnxb, mlp_w1, partb, /*N=*/9088, /*K=*/8192, /*Kreal=*/8192,
      /*ldb=*/9011, /*kchunk=*/2048, /*ntiles=*/71, /*slots=*/36);
  reduce_mlp1_k<<<dim3(9, 512), 256, 0, stream>>>(partb, mlp_b1, h3b, 9088, 9011, 512);

  // mlp2: [512,9088] @ [9011,8192], split-K 4 (chunks 36/36/36/34 steps).
  // XCD-mapped grid: 8 xcd * 32 slots = 256 blocks.
  gemm_splitk4<<<256, 512, 0, stream>>>(
      h3b, mlp_w2, partb, /*N=*/8192, /*K=*/9088, /*Kreal=*/9011,
      /*ldb=*/8192, /*kchunk=*/2304, /*ntiles=*/64, /*slots=*/32);
  reduce_mlp2_k<<<dim3(8, 512), 256, 0, stream>>>(partb, mlp_b2, x1b, (float*)d_out, 8192, 512);
}

// Round 6
// 792.673 us; speedup vs baseline: 1.0459x; 1.0459x over previous
//
#include <hip/hip_runtime.h>
#include <hip/hip_bf16.h>
#include <math.h>

typedef float f32x4 __attribute__((ext_vector_type(4)));
typedef float f32x2 __attribute__((ext_vector_type(2)));
typedef short s16x8 __attribute__((ext_vector_type(8)));
typedef short s16x4 __attribute__((ext_vector_type(4)));
typedef int   i32x4 __attribute__((ext_vector_type(4)));

__device__ __forceinline__ short f2bf(float f) {
  __hip_bfloat16 h = __float2bfloat16(f);
  return __builtin_bit_cast(short, h);
}
__device__ __forceinline__ float bf2f(short s) {
  __hip_bfloat16 h = __builtin_bit_cast(__hip_bfloat16, s);
  return __bfloat162float(h);
}
__device__ __forceinline__ float gelu_f(float x) {
  return 0.5f * x * (1.f + erff(x * 0.70710678118654752440f));
}
__device__ __forceinline__ float waveSum(float v) {
  #pragma unroll
  for (int d = 32; d; d >>= 1) v += __shfl_xor(v, d);
  return v;
}

// ---------------------------------------------------------------------------
// K1: dual LayerNorm over D=128 (qkv_ln and pin_ln) -> bf16 A-matrices
// ---------------------------------------------------------------------------
__global__ __launch_bounds__(256) void ln_dual_k(
    const float* __restrict__ x,
    const float* __restrict__ qg, const float* __restrict__ qb,
    const float* __restrict__ pg, const float* __restrict__ pb,
    short* __restrict__ lnq, short* __restrict__ lnp)
{
  int w = threadIdx.x >> 6, lane = threadIdx.x & 63;
  size_t row = (size_t)blockIdx.x * 4 + w;
  f32x2 v = reinterpret_cast<const f32x2*>(x + row * 128)[lane];
  float s  = v[0] + v[1];
  float sq = v[0]*v[0] + v[1]*v[1];
  s = waveSum(s); sq = waveSum(sq);
  float m = s * (1.f/128.f);
  float rstd = rsqrtf(sq * (1.f/128.f) - m*m + 1e-5f);
  int c = lane * 2;
  float a0 = (v[0]-m)*rstd, a1 = (v[1]-m)*rstd;
  unsigned q0 = (unsigned short)f2bf(a0*qg[c] + qb[c]);
  unsigned q1 = (unsigned short)f2bf(a1*qg[c+1] + qb[c+1]);
  unsigned p0 = (unsigned short)f2bf(a0*pg[c] + pb[c]);
  unsigned p1 = (unsigned short)f2bf(a1*pg[c+1] + pb[c+1]);
  ((unsigned*)lnq)[row*64 + lane] = q0 | (q1 << 16);
  ((unsigned*)lnp)[row*64 + lane] = p0 | (p1 << 16);
}

// ---------------------------------------------------------------------------
// K2: LayerNorm over 256 (attn_ln), fp32 in/out
// ---------------------------------------------------------------------------
__global__ __launch_bounds__(256) void ln256_k(
    const float* __restrict__ in,
    const float* __restrict__ g, const float* __restrict__ bb,
    float* __restrict__ out)
{
  int w = threadIdx.x >> 6, lane = threadIdx.x & 63;
  size_t row = (size_t)blockIdx.x * 4 + w;
  f32x4 v = reinterpret_cast<const f32x4*>(in + row * 256)[lane];
  float s  = v[0]+v[1]+v[2]+v[3];
  float sq = v[0]*v[0]+v[1]*v[1]+v[2]*v[2]+v[3]*v[3];
  s = waveSum(s); sq = waveSum(sq);
  float m = s * (1.f/256.f);
  float rstd = rsqrtf(sq * (1.f/256.f) - m*m + 1e-5f);
  f32x4 g4 = reinterpret_cast<const f32x4*>(g)[lane];
  f32x4 b4 = reinterpret_cast<const f32x4*>(bb)[lane];
  f32x4 o;
  #pragma unroll
  for (int k = 0; k < 4; ++k) o[k] = (v[k]-m)*rstd*g4[k] + b4[k];
  reinterpret_cast<f32x4*>(out + row * 256)[lane] = o;
}

// ---------------------------------------------------------------------------
// K3: LayerNorm over 8192 (mlp_ln) -> bf16
// ---------------------------------------------------------------------------
__global__ __launch_bounds__(256) void ln8192_k(
    const float* __restrict__ x1,
    const float* __restrict__ g, const float* __restrict__ bb,
    short* __restrict__ lnx)
{
  __shared__ float red[8];
  int t = threadIdx.x, w = t >> 6, lane = t & 63;
  int b = blockIdx.x;
  const f32x4* xr = reinterpret_cast<const f32x4*>(x1 + (size_t)b * 8192);
  f32x4 vals[8];
  float s = 0.f, sq = 0.f;
  #pragma unroll
  for (int i = 0; i < 8; ++i) {
    f32x4 v = xr[t + i*256];
    vals[i] = v;
    s  += v[0]+v[1]+v[2]+v[3];
    sq += v[0]*v[0]+v[1]*v[1]+v[2]*v[2]+v[3]*v[3];
  }
  s = waveSum(s); sq = waveSum(sq);
  if (lane == 0) { red[w] = s; red[4+w] = sq; }
  __syncthreads();
  s  = red[0]+red[1]+red[2]+red[3];
  sq = red[4]+red[5]+red[6]+red[7];
  float m = s * (1.f/8192.f);
  float rstd = rsqrtf(sq * (1.f/8192.f) - m*m + 1e-5f);
  #pragma unroll
  for (int i = 0; i < 8; ++i) {
    int idx = (t + i*256) * 4;
    f32x4 g4 = reinterpret_cast<const f32x4*>(g)[t + i*256];
    f32x4 b4 = reinterpret_cast<const f32x4*>(bb)[t + i*256];
    s16x4 o;
    #pragma unroll
    for (int k = 0; k < 4; ++k) o[k] = f2bf((vals[i][k]-m)*rstd*g4[k] + b4[k]);
    *reinterpret_cast<s16x4*>(&lnx[(size_t)b*8192 + idx]) = o;
  }
}

// ---------------------------------------------------------------------------
// Generic bf16-MFMA GEMM for the small GEMMs.
// EPI: 0 = bf16 out (+bias); 1 = f32 out (+bias); 2 = gelu split u/v (pin);
//      3 = f32 out (+bias +res)
// ---------------------------------------------------------------------------
template<int BM, int BN, int WM, int WN, int EPI>
__global__ __launch_bounds__(256) void gemm_k(
    const short* __restrict__ A, const float* __restrict__ Bw,
    const float* __restrict__ bias, const float* __restrict__ res,
    void* __restrict__ O0, void* __restrict__ O1,
    int M, int N, int K, int Nreal, int Kreal)
{
  constexpr int BK = 64;
  __shared__ __align__(16) short As[BM][BK + 8];
  __shared__ __align__(16) short Bs[BN][BK + 8];
  const int t = threadIdx.x;
  const int lane = t & 63;
  const int w = t >> 6;
  const int wm = w / WN, wn = w % WN;
  const int ln15 = lane & 15, hi = lane >> 4;
  const int m0 = blockIdx.y * BM;
  const int n0 = blockIdx.x * BN;

  f32x4 acc[4][4] = {};

  for (int k0 = 0; k0 < K; k0 += BK) {
    #pragma unroll
    for (int i = 0; i < (BM*BK)/(256*8); ++i) {
      int e = (i*256 + t) * 8;
      int r = e / BK, c = e % BK;
      *reinterpret_cast<i32x4*>(&As[r][c]) =
          *reinterpret_cast<const i32x4*>(&A[(size_t)(m0 + r) * K + k0 + c]);
    }
    #pragma unroll
    for (int i = 0; i < (BK*BN)/256; ++i) {
      int idx = i*256 + t;
      int n = idx % BN, k = idx / BN;
      int gk = k0 + k, gn = n0 + n;
      float v = (gk < Kreal && gn < Nreal) ? Bw[(size_t)gk * Nreal + gn] : 0.f;
      Bs[n][k] = f2bf(v);
    }
    __syncthreads();
    #pragma unroll
    for (int kk = 0; kk < BK; kk += 32) {
      s16x8 af[4], bfr[4];
      #pragma unroll
      for (int fm = 0; fm < 4; ++fm)
        af[fm] = *reinterpret_cast<const s16x8*>(&As[wm*64 + fm*16 + ln15][kk + hi*8]);
      #pragma unroll
      for (int fn = 0; fn < 4; ++fn)
        bfr[fn] = *reinterpret_cast<const s16x8*>(&Bs[wn*64 + fn*16 + ln15][kk + hi*8]);
      #pragma unroll
      for (int fm = 0; fm < 4; ++fm)
        #pragma unroll
        for (int fn = 0; fn < 4; ++fn)
          acc[fm][fn] = __builtin_amdgcn_mfma_f32_16x16x32_bf16(
              af[fm], bfr[fn], acc[fm][fn], 0, 0, 0);
    }
    __syncthreads();
  }

  #pragma unroll
  for (int fm = 0; fm < 4; ++fm) {
    #pragma unroll
    for (int fn = 0; fn < 4; ++fn) {
      #pragma unroll
      for (int j = 0; j < 4; ++j) {
        int row = m0 + wm*64 + fm*16 + hi*4 + j;
        int col = n0 + wn*64 + fn*16 + ln15;
        float v = acc[fm][fn][j];
        if constexpr (EPI == 0) {
          v += bias[col];
          ((short*)O0)[(size_t)row * N + col] = f2bf(v);
        } else if constexpr (EPI == 1) {
          v += bias[col];
          ((float*)O0)[(size_t)row * N + col] = v;
        } else if constexpr (EPI == 2) {
          v = gelu_f(v + bias[col]);
          if (col < 256) ((float*)O0)[(size_t)row * 256 + col] = v;
          else ((short*)O1)[(size_t)row * 256 + (col - 256)] = f2bf(v);
        } else { // 3
          v += bias[col] + res[(size_t)row * N + col];
          ((float*)O0)[(size_t)row * N + col] = v;
        }
      }
    }
  }
}

// ---------------------------------------------------------------------------
// Split-K GEMM v5 for the fat MLP GEMMs.
// BM=512 (all of M), BN=128, BK=64; 512 threads / 8 waves; acc[4][8]/wave.
// KEY CHANGE vs v4: A is NOT staged in LDS. Each wave loads its 8 MFMA
// A-fragments directly global->VGPR per step (16 rows x 64B contiguous per
// instruction; A is 8.4-9.3 MB, L2/LLC-resident since all blocks stream the
// same slab in near-lockstep). This cuts LDS traffic 3x and LDS size to
// 2 x 16 KB (double-buffered B only, XOR-swizzled, conflict-free).
// Pipeline per step (ONE barrier): loadA(s) [issued first so its vmcnt wait
// doesn't drain the B prefetch] -> loadB(s+1) -> MFMA -> writeB(other buf)
// -> barrier.
// ---------------------------------------------------------------------------
__global__ __launch_bounds__(512, 2) void gemm_splitk5(
    const short* __restrict__ A, const float* __restrict__ Bw,
    float* __restrict__ part,
    int N, int K, int Kreal, int ldb, int kchunk, int ntiles)
{
  __shared__ __align__(16) short Bs[2][128 * 64];  // 2 x 16 KB
  const int t = threadIdx.x, lane = t & 63, w = t >> 6;
  const int ln15 = lane & 15, hi = lane >> 4;
  const int nt = blockIdx.x % ntiles, z = blockIdx.x / ntiles;
  const int n0 = nt * 128;
  const int kbeg = z * kchunk;
  const int kend = (kbeg + kchunk < K) ? (kbeg + kchunk) : K;
  const int nsteps = (kend - kbeg) >> 6;

  // B staging: thread handles col bn, 2 k-octet granules starting at bg0
  const int bn = t & 127;
  const int bg0 = (t >> 7) * 2;
  const bool bok = (n0 + bn) < ldb;
  const int bsw = bn & 7;                    // XOR swizzle key

  float br[16];
  auto loadB = [&](int k0) {
    const float* bp = Bw + (size_t)(k0 + bg0 * 8) * ldb + n0 + bn;
    #pragma unroll
    for (int m = 0; m < 16; ++m) {
      int gk = k0 + bg0 * 8 + m;
      br[m] = (bok && gk < Kreal) ? bp[(size_t)m * ldb] : 0.f;
    }
  };
  auto writeB = [&](int buf) {
    s16x8 v0, v1;
    #pragma unroll
    for (int m = 0; m < 8; ++m) { v0[m] = f2bf(br[m]); v1[m] = f2bf(br[8 + m]); }
    short* dst = &Bs[buf][bn * 64];
    *reinterpret_cast<s16x8*>(dst + ((bg0    ) ^ bsw) * 8) = v0;
    *reinterpret_cast<s16x8*>(dst + ((bg0 + 1) ^ bsw) * 8) = v1;
  };

  f32x4 acc[4][8] = {};

  loadB(kbeg);
  writeB(0);
  __syncthreads();

  for (int s = 0; s < nsteps; ++s) {
    const int k0 = kbeg + s * 64;
    // A fragments for THIS step, direct from global (L2). Issued before the
    // B prefetch so the MFMA's vmcnt wait leaves B loads in flight.
    s16x8 af[8];
    #pragma unroll
    for (int kk = 0; kk < 2; ++kk)
      #pragma unroll
      for (int fm = 0; fm < 4; ++fm) {
        int row = w * 64 + fm * 16 + ln15;
        af[kk * 4 + fm] = *reinterpret_cast<const s16x8*>(
            &A[(size_t)row * K + k0 + (kk * 4 + hi) * 8]);
      }
    if (s + 1 < nsteps) loadB(k0 + 64);

    const short* bsrc = &Bs[s & 1][0];
    #pragma unroll
    for (int kk = 0; kk < 2; ++kk) {
      const int g = kk * 4 + hi;
      #pragma unroll
      for (int fn = 0; fn < 8; ++fn) {
        int row = fn * 16 + ln15;
        s16x8 bv = *reinterpret_cast<const s16x8*>(
            &bsrc[row * 64 + ((g ^ (row & 7)) * 8)]);
        #pragma unroll
        for (int fm = 0; fm < 4; ++fm)
          acc[fm][fn] = __builtin_amdgcn_mfma_f32_16x16x32_bf16(
              af[kk * 4 + fm], bv, acc[fm][fn], 0, 0, 0);
      }
    }
    if (s + 1 < nsteps) writeB((s + 1) & 1);   // other buffer; no LDS conflict
    __syncthreads();
  }

  #pragma unroll
  for (int fm = 0; fm < 4; ++fm)
    #pragma unroll
    for (int fn = 0; fn < 8; ++fn)
      #pragma unroll
      for (int j = 0; j < 4; ++j) {
        int row = w * 64 + fm * 16 + hi * 4 + j;
        int col = n0 + fn * 16 + ln15;
        part[((size_t)z * 512 + row) * N + col] = acc[fm][fn][j];
      }
}

// ---------------------------------------------------------------------------
// split-K reduce for mlp1: h3 = gelu(sum_ks part + b1), bf16, col<Nreal guard
// ---------------------------------------------------------------------------
__global__ __launch_bounds__(256) void reduce_mlp1_k(
    const float* __restrict__ part, const float* __restrict__ bias,
    short* __restrict__ h3, int N, int Nreal, int M, int ks)
{
  int col4 = (blockIdx.x * 256 + threadIdx.x) * 4;
  int row = blockIdx.y;
  if (col4 >= N) return;
  size_t base = (size_t)row * N + col4;
  size_t stride = (size_t)M * N;
  f32x4 s = *reinterpret_cast<const f32x4*>(part + base);
  for (int k = 1; k < ks; ++k)
    s += *reinterpret_cast<const f32x4*>(part + base + (size_t)k * stride);
  s16x4 o;
  #pragma unroll
  for (int j = 0; j < 4; ++j) {
    int c = col4 + j;
    float v = 0.f;
    if (c < Nreal) v = gelu_f(s[j] + bias[c]);
    o[j] = f2bf(v);
  }
  *reinterpret_cast<s16x4*>(h3 + base) = o;
}

// ---------------------------------------------------------------------------
// split-K reduce for mlp2: out = sum_ks part + b2 + x1 (f32)
// ---------------------------------------------------------------------------
__global__ __launch_bounds__(256) void reduce_mlp2_k(
    const float* __restrict__ part, const float* __restrict__ bias,
    const float* __restrict__ x1, float* __restrict__ out, int N, int M, int ks)
{
  int col4 = (blockIdx.x * 256 + threadIdx.x) * 4;
  int row = blockIdx.y;
  size_t base = (size_t)row * N + col4;
  size_t stride = (size_t)M * N;
  f32x4 s = *reinterpret_cast<const f32x4*>(part + base);
  for (int k = 1; k < ks; ++k)
    s += *reinterpret_cast<const f32x4*>(part + base + (size_t)k * stride);
  f32x4 b4 = *reinterpret_cast<const f32x4*>(bias + col4);
  f32x4 r4 = *reinterpret_cast<const f32x4*>(x1 + base);
  #pragma unroll
  for (int j = 0; j < 4; ++j) s[j] += b4[j] + r4[j];
  *reinterpret_cast<f32x4*>(out + base) = s;
}

// ---------------------------------------------------------------------------
// K4: fused tiny attention
// ---------------------------------------------------------------------------
__global__ __launch_bounds__(256) void attn_k(
    const short* __restrict__ qkv, const float* __restrict__ relb,
    const float* __restrict__ scale_p, short* __restrict__ av)
{
  __shared__ __align__(16) short qlds[64][136];
  __shared__ __align__(16) short klds[64][136];
  __shared__ __align__(16) short plds[64][72];
  __shared__ __align__(16) short vlds[128][72];
  __shared__ float rb[127];
  int t = threadIdx.x, lane = t & 63, w = t >> 6;
  int ln15 = lane & 15, hi = lane >> 4;
  int b = blockIdx.x;
  if (t < 127) rb[t] = relb[t];

  f32x4 sacc[4] = {};
  for (int kc = 0; kc < 4; ++kc) {
    #pragma unroll
    for (int i = 0; i < 4; ++i) {
      int e = (i*256 + t) * 8;
      int r = e >> 7, c = e & 127;
      size_t base = (size_t)(b*64 + r) * 1536 + kc*128 + c;
      *reinterpret_cast<i32x4*>(&qlds[r][c]) = *reinterpret_cast<const i32x4*>(&qkv[base]);
      *reinterpret_cast<i32x4*>(&klds[r][c]) = *reinterpret_cast<const i32x4*>(&qkv[base + 512]);
    }
    __syncthreads();
    #pragma unroll
    for (int kk = 0; kk < 128; kk += 32) {
      s16x8 aq = *reinterpret_cast<const s16x8*>(&qlds[16*w + ln15][kk + hi*8]);
      #pragma unroll
      for (int fn = 0; fn < 4; ++fn) {
        s16x8 bk = *reinterpret_cast<const s16x8*>(&klds[fn*16 + ln15][kk + hi*8]);
        sacc[fn] = __builtin_amdgcn_mfma_f32_16x16x32_bf16(aq, bk, sacc[fn], 0, 0, 0);
      }
    }
    __syncthreads();
  }

  float scale = scale_p[0];
  #pragma unroll
  for (int j = 0; j < 4; ++j) {
    int row = 16*w + hi*4 + j;
    float pv[4];
    float mx = -1e30f;
    #pragma unroll
    for (int fn = 0; fn < 4; ++fn) {
      int col = fn*16 + ln15;
      pv[fn] = sacc[fn][j] + rb[col - row + 63];
      mx = fmaxf(mx, pv[fn]);
    }
    #pragma unroll
    for (int d = 1; d < 16; d <<= 1) mx = fmaxf(mx, __shfl_xor(mx, d));
    float sum = 0.f;
    #pragma unroll
    for (int fn = 0; fn < 4; ++fn) { pv[fn] = __expf(pv[fn] - mx); sum += pv[fn]; }
    #pragma unroll
    for (int d = 1; d < 16; d <<= 1) sum += __shfl_xor(sum, d);
    float inv = scale / sum;
    #pragma unroll
    for (int fn = 0; fn < 4; ++fn) plds[row][fn*16 + ln15] = f2bf(pv[fn] * inv);
  }
  __syncthreads();

  for (int cc = 0; cc < 4; ++cc) {
    #pragma unroll
    for (int i = 0; i < 8; ++i) {
      int idx = i*256 + t;
      int s = idx >> 5, c4 = (idx & 31) * 4;
      s16x4 vw = *reinterpret_cast<const s16x4*>(
          &qkv[(size_t)(b*64 + s) * 1536 + 1024 + cc*128 + c4]);
      vlds[c4+0][s] = vw[0]; vlds[c4+1][s] = vw[1];
      vlds[c4+2][s] = vw[2]; vlds[c4+3][s] = vw[3];
    }
    __syncthreads();
    f32x4 pacc[8] = {};
    #pragma unroll
    for (int kk = 0; kk < 64; kk += 32) {
      s16x8 ap = *reinterpret_cast<const s16x8*>(&plds[16*w + ln15][kk + hi*8]);
      #pragma unroll
      for (int fn = 0; fn < 8; ++fn) {
        s16x8 bv = *reinterpret_cast<const s16x8*>(&vlds[fn*16 + ln15][kk + hi*8]);
        pacc[fn] = __builtin_amdgcn_mfma_f32_16x16x32_bf16(ap, bv, pacc[fn], 0, 0, 0);
      }
    }
    #pragma unroll
    for (int fn = 0; fn < 8; ++fn)
      #pragma unroll
      for (int j = 0; j < 4; ++j) {
        int row = b*64 + 16*w + hi*4 + j;
        int col = cc*128 + fn*16 + ln15;
        av[(size_t)row * 512 + col] = f2bf(pacc[fn][j]);
      }
    __syncthreads();
  }
}

// ---------------------------------------------------------------------------
// K5: SGU gate
// ---------------------------------------------------------------------------
__global__ __launch_bounds__(256) void gate_k(
    const float* __restrict__ u, const short* __restrict__ vbf,
    const float* __restrict__ a,
    const float* __restrict__ spg_g, const float* __restrict__ spg_b,
    const float* __restrict__ spw, const float* __restrict__ spb,
    const float* __restrict__ pog, const float* __restrict__ pob,
    short* __restrict__ outn)
{
  __shared__ __align__(16) short nvb[256][72];
  __shared__ __align__(16) short spwT[64][72];
  __shared__ float s_spg[64], s_spbl[64], s_spb[64];
  __shared__ float s_pog[256], s_pob[256];
  int t = threadIdx.x, lane = t & 63, w = t >> 6;
  int ln15 = lane & 15, hi = lane >> 4;
  int b = blockIdx.x;

  if (t < 64) { s_spg[t] = spg_g[t]; s_spbl[t] = spg_b[t]; s_spb[t] = spb[t]; }
  s_pog[t] = pog[t]; s_pob[t] = pob[t];
  #pragma unroll
  for (int i = 0; i < 16; ++i) {
    int idx = i*256 + t;
    int sr = idx >> 6, tc = idx & 63;
    spwT[tc][sr] = f2bf(spw[idx]);
  }

  float vvv[64];
  {
    int c = t;
    float s = 0.f, sq = 0.f;
    #pragma unroll
    for (int si = 0; si < 64; ++si) {
      float f = bf2f(vbf[(size_t)(b*64 + si) * 256 + c]);
      vvv[si] = f; s += f; sq += f*f;
    }
    float m = s * (1.f/64.f);
    float rstd = rsqrtf(sq * (1.f/64.f) - m*m + 1e-5f);
    __syncthreads();
    #pragma unroll
    for (int si = 0; si < 64; ++si)
      nvb[c][si] = f2bf((vvv[si]-m)*rstd*s_spg[si] + s_spbl[si]);
  }
  __syncthreads();

  f32x4 yacc[4][4] = {};
  #pragma unroll
  for (int kk = 0; kk < 64; kk += 32) {
    s16x8 af[4], bfr[4];
    #pragma unroll
    for (int fm = 0; fm < 4; ++fm)
      af[fm] = *reinterpret_cast<const s16x8*>(&nvb[64*w + fm*16 + ln15][kk + hi*8]);
    #pragma unroll
    for (int fn = 0; fn < 4; ++fn)
      bfr[fn] = *reinterpret_cast<const s16x8*>(&spwT[fn*16 + ln15][kk + hi*8]);
    #pragma unroll
    for (int fm = 0; fm < 4; ++fm)
      #pragma unroll
      for (int fn = 0; fn < 4; ++fn)
        yacc[fm][fn] = __builtin_amdgcn_mfma_f32_16x16x32_bf16(
            af[fm], bfr[fn], yacc[fm][fn], 0, 0, 0);
  }
  __syncthreads();

  short (*outl)[264] = reinterpret_cast<short(*)[264]>(&nvb[0][0]);
  #pragma unroll
  for (int fm = 0; fm < 4; ++fm) {
    #pragma unroll
    for (int fn = 0; fn < 4; ++fn) {
      int crow = 64*w + fm*16 + hi*4;
      int tcol = fn*16 + ln15;
      f32x4 u4 = *reinterpret_cast<const f32x4*>(&u[(size_t)(b*64 + tcol)*256 + crow]);
      f32x4 a4 = *reinterpret_cast<const f32x4*>(&a[(size_t)(b*64 + tcol)*256 + crow]);
      #pragma unroll
      for (int j = 0; j < 4; ++j) {
        float g = gelu_f(yacc[fm][fn][j] + s_spb[tcol]);
        float o = u4[j] * (g + a4[j]);
        outl[tcol][crow + j] = f2bf(o);
      }
    }
  }
  __syncthreads();

  #pragma unroll
  for (int ri = 0; ri < 16; ++ri) {
    int trow = w*16 + ri;
    int c = lane * 4;
    s16x4 raw = *reinterpret_cast<const s16x4*>(&outl[trow][c]);
    float f0 = bf2f(raw[0]), f1 = bf2f(raw[1]), f2 = bf2f(raw[2]), f3 = bf2f(raw[3]);
    float s  = f0+f1+f2+f3;
    float sq = f0*f0+f1*f1+f2*f2+f3*f3;
    s = waveSum(s); sq = waveSum(sq);
    float m = s * (1.f/256.f);
    float rstd = rsqrtf(sq * (1.f/256.f) - m*m + 1e-5f);
    s16x4 o;
    o[0] = f2bf((f0-m)*rstd*s_pog[c+0] + s_pob[c+0]);
    o[1] = f2bf((f1-m)*rstd*s_pog[c+1] + s_pob[c+1]);
    o[2] = f2bf((f2-m)*rstd*s_pog[c+2] + s_pob[c+2]);
    o[3] = f2bf((f3-m)*rstd*s_pog[c+3] + s_pob[c+3]);
    *reinterpret_cast<s16x4*>(&outn[(size_t)(b*64 + trow)*256 + c]) = o;
  }
}

// ---------------------------------------------------------------------------
extern "C" void kernel_launch(void* const* d_in, const int* in_sizes, int n_in,
                              void* d_out, int out_size, void* d_ws, size_t ws_size,
                              hipStream_t stream)
{
  const float* x          = (const float*)d_in[0];
  const float* qkv_ln_g   = (const float*)d_in[1];
  const float* qkv_ln_b   = (const float*)d_in[2];
  const float* qkv_w      = (const float*)d_in[3];
  const float* qkv_b      = (const float*)d_in[4];
  const float* attn_pw    = (const float*)d_in[5];
  const float* attn_pb    = (const float*)d_in[6];
  const float* attn_ln_g  = (const float*)d_in[7];
  const float* attn_ln_b  = (const float*)d_in[8];
  const float* rel_bias   = (const float*)d_in[9];
  const float* scale      = (const float*)d_in[10];
  const float* pin_ln_g   = (const float*)d_in[11];
  const float* pin_ln_b   = (const float*)d_in[12];
  const float* pin_w      = (const float*)d_in[13];
  const float* pin_b      = (const float*)d_in[14];
  const float* sp_ln_g    = (const float*)d_in[15];
  const float* sp_ln_b    = (const float*)d_in[16];
  const float* sp_w       = (const float*)d_in[17];
  const float* sp_b       = (const float*)d_in[18];
  const float* pout_ln_g  = (const float*)d_in[19];
  const float* pout_ln_b  = (const float*)d_in[20];
  const float* pout_w     = (const float*)d_in[21];
  const float* pout_b     = (const float*)d_in[22];
  const float* mlp_ln_g   = (const float*)d_in[23];
  const float* mlp_ln_b   = (const float*)d_in[24];
  const float* mlp_w1     = (const float*)d_in[25];
  const float* mlp_b1     = (const float*)d_in[26];
  const float* mlp_w2     = (const float*)d_in[27];
  const float* mlp_b2     = (const float*)d_in[28];

  char* ws = (char*)d_ws;
  short* lnq  = (short*)(ws + 0);            // 8.39 MB
  short* lnp  = (short*)(ws + 8388608);      // 8.39 MB
  short* qkvb = (short*)(ws + 16777216);     // 100.7 MB (dead after attn)
  short* avb  = (short*)(ws + 117440512);    // 33.6 MB
  float* projb= (float*)(ws + 16777216);     // alias qkv region
  float* ab   = (float*)(ws + 50331648);     // alias qkv region
  float* ub   = (float*)(ws + 83886080);     // alias qkv region
  short* vbfb = (short*)(ws + 117440512);    // alias av region
  short* outnb= (short*)(ws + 134217728);    // alias av region
  float* x1b  = (float*)(ws + 0);            // alias lnq/lnp region [0,16.8MB)
  short* lnxb = (short*)(ws + 150994944);    // 8.39 MB
  short* h3b  = (short*)(ws + 159383552);    // 9.31 MB (512 x 9088, pad zeroed)
  float* partb= (float*)(ws + 16777216);     // split-K partials (<=67 MB)

  ln_dual_k<<<8192, 256, 0, stream>>>(x, qkv_ln_g, qkv_ln_b, pin_ln_g, pin_ln_b, lnq, lnp);
  gemm_k<128,128,2,2,0><<<dim3(12,256), 256, 0, stream>>>(
      lnq, qkv_w, qkv_b, nullptr, qkvb, nullptr, 32768, 1536, 128, 1536, 128);
  attn_k<<<512, 256, 0, stream>>>(qkvb, rel_bias, scale, avb);
  gemm_k<128,128,2,2,1><<<dim3(2,256), 256, 0, stream>>>(
      avb, attn_pw, attn_pb, nullptr, projb, nullptr, 32768, 256, 512, 256, 512);
  ln256_k<<<8192, 256, 0, stream>>>(projb, attn_ln_g, attn_ln_b, ab);
  gemm_k<128,128,2,2,2><<<dim3(4,256), 256, 0, stream>>>(
      lnp, pin_w, pin_b, nullptr, ub, vbfb, 32768, 512, 128, 512, 128);
  gate_k<<<512, 256, 0, stream>>>(ub, vbfb, ab, sp_ln_g, sp_ln_b, sp_w, sp_b,
                                  pout_ln_g, pout_ln_b, outnb);
  gemm_k<128,128,2,2,3><<<dim3(1,256), 256, 0, stream>>>(
      outnb, pout_w, pout_b, x, x1b, nullptr, 32768, 128, 256, 128, 256);
  ln8192_k<<<512, 256, 0, stream>>>(x1b, mlp_ln_g, mlp_ln_b, lnxb);

  // mlp1: [512,8192] @ [8192,9011] (N padded 9088 = 71*128), split-K 3.
  // 213 blocks <= 256 CUs -> no 2-deep serialization; chunks 43/43/42 steps.
  gemm_splitk5<<<213, 512, 0, stream>>>(
      lnxb, mlp_w1, partb, /*N=*/9088, /*K=*/8192, /*Kreal=*/8192,
      /*ldb=*/9011, /*kchunk=*/2752, /*ntiles=*/71);
  reduce_mlp1_k<<<dim3(9, 512), 256, 0, stream>>>(partb, mlp_b1, h3b, 9088, 9011, 512, 3);

  // mlp2: [512,9088] @ [9011,8192], split-K 4 (256 blocks; 36/36/36/34 steps).
  gemm_splitk5<<<256, 512, 0, stream>>>(
      h3b, mlp_w2, partb, /*N=*/8192, /*K=*/9088, /*Kreal=*/9011,
      /*ldb=*/8192, /*kchunk=*/2304, /*ntiles=*/64);
  reduce_mlp2_k<<<dim3(8, 512), 256, 0, stream>>>(partb, mlp_b2, x1b, (float*)d_out, 8192, 512, 4);
}

// Round 7
// 785.209 us; speedup vs baseline: 1.0558x; 1.0095x over previous
//
#include <hip/hip_runtime.h>
#include <hip/hip_bf16.h>
#include <math.h>

typedef float f32x4 __attribute__((ext_vector_type(4)));
typedef float f32x2 __attribute__((ext_vector_type(2)));
typedef short s16x8 __attribute__((ext_vector_type(8)));
typedef short s16x4 __attribute__((ext_vector_type(4)));
typedef int   i32x4 __attribute__((ext_vector_type(4)));

__device__ __forceinline__ short f2bf(float f) {
  __hip_bfloat16 h = __float2bfloat16(f);
  return __builtin_bit_cast(short, h);
}
__device__ __forceinline__ float bf2f(short s) {
  __hip_bfloat16 h = __builtin_bit_cast(__hip_bfloat16, s);
  return __bfloat162float(h);
}
__device__ __forceinline__ float gelu_f(float x) {
  return 0.5f * x * (1.f + erff(x * 0.70710678118654752440f));
}
__device__ __forceinline__ float waveSum(float v) {
  #pragma unroll
  for (int d = 32; d; d >>= 1) v += __shfl_xor(v, d);
  return v;
}

// ---------------------------------------------------------------------------
// K1: dual LayerNorm over D=128 (qkv_ln and pin_ln) -> bf16 A-matrices
// ---------------------------------------------------------------------------
__global__ __launch_bounds__(256) void ln_dual_k(
    const float* __restrict__ x,
    const float* __restrict__ qg, const float* __restrict__ qb,
    const float* __restrict__ pg, const float* __restrict__ pb,
    short* __restrict__ lnq, short* __restrict__ lnp)
{
  int w = threadIdx.x >> 6, lane = threadIdx.x & 63;
  size_t row = (size_t)blockIdx.x * 4 + w;
  f32x2 v = reinterpret_cast<const f32x2*>(x + row * 128)[lane];
  float s  = v[0] + v[1];
  float sq = v[0]*v[0] + v[1]*v[1];
  s = waveSum(s); sq = waveSum(sq);
  float m = s * (1.f/128.f);
  float rstd = rsqrtf(sq * (1.f/128.f) - m*m + 1e-5f);
  int c = lane * 2;
  float a0 = (v[0]-m)*rstd, a1 = (v[1]-m)*rstd;
  unsigned q0 = (unsigned short)f2bf(a0*qg[c] + qb[c]);
  unsigned q1 = (unsigned short)f2bf(a1*qg[c+1] + qb[c+1]);
  unsigned p0 = (unsigned short)f2bf(a0*pg[c] + pb[c]);
  unsigned p1 = (unsigned short)f2bf(a1*pg[c+1] + pb[c+1]);
  ((unsigned*)lnq)[row*64 + lane] = q0 | (q1 << 16);
  ((unsigned*)lnp)[row*64 + lane] = p0 | (p1 << 16);
}

// ---------------------------------------------------------------------------
// K2: LayerNorm over 256 (attn_ln), fp32 in/out
// ---------------------------------------------------------------------------
__global__ __launch_bounds__(256) void ln256_k(
    const float* __restrict__ in,
    const float* __restrict__ g, const float* __restrict__ bb,
    float* __restrict__ out)
{
  int w = threadIdx.x >> 6, lane = threadIdx.x & 63;
  size_t row = (size_t)blockIdx.x * 4 + w;
  f32x4 v = reinterpret_cast<const f32x4*>(in + row * 256)[lane];
  float s  = v[0]+v[1]+v[2]+v[3];
  float sq = v[0]*v[0]+v[1]*v[1]+v[2]*v[2]+v[3]*v[3];
  s = waveSum(s); sq = waveSum(sq);
  float m = s * (1.f/256.f);
  float rstd = rsqrtf(sq * (1.f/256.f) - m*m + 1e-5f);
  f32x4 g4 = reinterpret_cast<const f32x4*>(g)[lane];
  f32x4 b4 = reinterpret_cast<const f32x4*>(bb)[lane];
  f32x4 o;
  #pragma unroll
  for (int k = 0; k < 4; ++k) o[k] = (v[k]-m)*rstd*g4[k] + b4[k];
  reinterpret_cast<f32x4*>(out + row * 256)[lane] = o;
}

// ---------------------------------------------------------------------------
// K3: LayerNorm over 8192 (mlp_ln) -> bf16
// ---------------------------------------------------------------------------
__global__ __launch_bounds__(256) void ln8192_k(
    const float* __restrict__ x1,
    const float* __restrict__ g, const float* __restrict__ bb,
    short* __restrict__ lnx)
{
  __shared__ float red[8];
  int t = threadIdx.x, w = t >> 6, lane = t & 63;
  int b = blockIdx.x;
  const f32x4* xr = reinterpret_cast<const f32x4*>(x1 + (size_t)b * 8192);
  f32x4 vals[8];
  float s = 0.f, sq = 0.f;
  #pragma unroll
  for (int i = 0; i < 8; ++i) {
    f32x4 v = xr[t + i*256];
    vals[i] = v;
    s  += v[0]+v[1]+v[2]+v[3];
    sq += v[0]*v[0]+v[1]*v[1]+v[2]*v[2]+v[3]*v[3];
  }
  s = waveSum(s); sq = waveSum(sq);
  if (lane == 0) { red[w] = s; red[4+w] = sq; }
  __syncthreads();
  s  = red[0]+red[1]+red[2]+red[3];
  sq = red[4]+red[5]+red[6]+red[7];
  float m = s * (1.f/8192.f);
  float rstd = rsqrtf(sq * (1.f/8192.f) - m*m + 1e-5f);
  #pragma unroll
  for (int i = 0; i < 8; ++i) {
    int idx = (t + i*256) * 4;
    f32x4 g4 = reinterpret_cast<const f32x4*>(g)[t + i*256];
    f32x4 b4 = reinterpret_cast<const f32x4*>(bb)[t + i*256];
    s16x4 o;
    #pragma unroll
    for (int k = 0; k < 4; ++k) o[k] = f2bf((vals[i][k]-m)*rstd*g4[k] + b4[k]);
    *reinterpret_cast<s16x4*>(&lnx[(size_t)b*8192 + idx]) = o;
  }
}

// ---------------------------------------------------------------------------
// Generic bf16-MFMA GEMM for the small GEMMs.
// EPI: 0 = bf16 out (+bias); 1 = f32 out (+bias); 2 = gelu split u/v (pin);
//      3 = f32 out (+bias +res)
// ---------------------------------------------------------------------------
template<int BM, int BN, int WM, int WN, int EPI>
__global__ __launch_bounds__(256) void gemm_k(
    const short* __restrict__ A, const float* __restrict__ Bw,
    const float* __restrict__ bias, const float* __restrict__ res,
    void* __restrict__ O0, void* __restrict__ O1,
    int M, int N, int K, int Nreal, int Kreal)
{
  constexpr int BK = 64;
  __shared__ __align__(16) short As[BM][BK + 8];
  __shared__ __align__(16) short Bs[BN][BK + 8];
  const int t = threadIdx.x;
  const int lane = t & 63;
  const int w = t >> 6;
  const int wm = w / WN, wn = w % WN;
  const int ln15 = lane & 15, hi = lane >> 4;
  const int m0 = blockIdx.y * BM;
  const int n0 = blockIdx.x * BN;

  f32x4 acc[4][4] = {};

  for (int k0 = 0; k0 < K; k0 += BK) {
    #pragma unroll
    for (int i = 0; i < (BM*BK)/(256*8); ++i) {
      int e = (i*256 + t) * 8;
      int r = e / BK, c = e % BK;
      *reinterpret_cast<i32x4*>(&As[r][c]) =
          *reinterpret_cast<const i32x4*>(&A[(size_t)(m0 + r) * K + k0 + c]);
    }
    #pragma unroll
    for (int i = 0; i < (BK*BN)/256; ++i) {
      int idx = i*256 + t;
      int n = idx % BN, k = idx / BN;
      int gk = k0 + k, gn = n0 + n;
      float v = (gk < Kreal && gn < Nreal) ? Bw[(size_t)gk * Nreal + gn] : 0.f;
      Bs[n][k] = f2bf(v);
    }
    __syncthreads();
    #pragma unroll
    for (int kk = 0; kk < BK; kk += 32) {
      s16x8 af[4], bfr[4];
      #pragma unroll
      for (int fm = 0; fm < 4; ++fm)
        af[fm] = *reinterpret_cast<const s16x8*>(&As[wm*64 + fm*16 + ln15][kk + hi*8]);
      #pragma unroll
      for (int fn = 0; fn < 4; ++fn)
        bfr[fn] = *reinterpret_cast<const s16x8*>(&Bs[wn*64 + fn*16 + ln15][kk + hi*8]);
      #pragma unroll
      for (int fm = 0; fm < 4; ++fm)
        #pragma unroll
        for (int fn = 0; fn < 4; ++fn)
          acc[fm][fn] = __builtin_amdgcn_mfma_f32_16x16x32_bf16(
              af[fm], bfr[fn], acc[fm][fn], 0, 0, 0);
    }
    __syncthreads();
  }

  #pragma unroll
  for (int fm = 0; fm < 4; ++fm) {
    #pragma unroll
    for (int fn = 0; fn < 4; ++fn) {
      #pragma unroll
      for (int j = 0; j < 4; ++j) {
        int row = m0 + wm*64 + fm*16 + hi*4 + j;
        int col = n0 + wn*64 + fn*16 + ln15;
        float v = acc[fm][fn][j];
        if constexpr (EPI == 0) {
          v += bias[col];
          ((short*)O0)[(size_t)row * N + col] = f2bf(v);
        } else if constexpr (EPI == 1) {
          v += bias[col];
          ((float*)O0)[(size_t)row * N + col] = v;
        } else if constexpr (EPI == 2) {
          v = gelu_f(v + bias[col]);
          if (col < 256) ((float*)O0)[(size_t)row * 256 + col] = v;
          else ((short*)O1)[(size_t)row * 256 + (col - 256)] = f2bf(v);
        } else { // 3
          v += bias[col] + res[(size_t)row * N + col];
          ((float*)O0)[(size_t)row * N + col] = v;
        }
      }
    }
  }
}

// ---------------------------------------------------------------------------
// Split-K GEMM v6 for the fat MLP GEMMs.
// Same tiling as v5 (BM=512, BN=128, BK=64, 8 waves, A direct global->VGPR,
// B double-buffered in LDS with XOR swizzle, conflict-free).
// KEY CHANGE vs v5: write-early / load-late. Per step s:
//   1. issue A loads (step s)                    [L2]
//   2. writeB(s+1) from br  -- B loads were issued a FULL STEP earlier, so
//      the compiler's wait is vmcnt(8) (A still in flight) and nearly free
//   3. loadB(s+2) into br   -- single staging set, regs just freed
//   4. MFMA on buf s&1      -- vmcnt(16): B(s+2) stays in flight
//   5. one barrier
// B prefetch now spans ~1 full step instead of only the MFMA phase.
// ---------------------------------------------------------------------------
__global__ __launch_bounds__(512, 2) void gemm_splitk6(
    const short* __restrict__ A, const float* __restrict__ Bw,
    float* __restrict__ part,
    int N, int K, int Kreal, int ldb, int kchunk, int ntiles)
{
  __shared__ __align__(16) short Bs[2][128 * 64];  // 2 x 16 KB
  const int t = threadIdx.x, lane = t & 63, w = t >> 6;
  const int ln15 = lane & 15, hi = lane >> 4;
  const int nt = blockIdx.x % ntiles, z = blockIdx.x / ntiles;
  const int n0 = nt * 128;
  const int kbeg = z * kchunk;
  const int kend = (kbeg + kchunk < K) ? (kbeg + kchunk) : K;
  const int nsteps = (kend - kbeg) >> 6;

  const int bn = t & 127;
  const int bg0 = (t >> 7) * 2;
  const bool bok = (n0 + bn) < ldb;
  const int bsw = bn & 7;                    // XOR swizzle key

  float br[16];
  auto loadB = [&](int k0) {
    const float* bp = Bw + (size_t)(k0 + bg0 * 8) * ldb + n0 + bn;
    #pragma unroll
    for (int m = 0; m < 16; ++m) {
      int gk = k0 + bg0 * 8 + m;
      br[m] = (bok && gk < Kreal) ? bp[(size_t)m * ldb] : 0.f;
    }
  };
  auto writeB = [&](int buf) {
    s16x8 v0, v1;
    #pragma unroll
    for (int m = 0; m < 8; ++m) { v0[m] = f2bf(br[m]); v1[m] = f2bf(br[8 + m]); }
    short* dst = &Bs[buf][bn * 64];
    *reinterpret_cast<s16x8*>(dst + ((bg0    ) ^ bsw) * 8) = v0;
    *reinterpret_cast<s16x8*>(dst + ((bg0 + 1) ^ bsw) * 8) = v1;
  };

  f32x4 acc[4][8] = {};

  // prologue: buf0 <- B(step 0); br <- B(step 1)
  loadB(kbeg);
  writeB(0);
  if (nsteps > 1) loadB(kbeg + 64);
  __syncthreads();

  for (int s = 0; s < nsteps; ++s) {
    const int k0 = kbeg + s * 64;
    // 1. A fragments for THIS step (L2-resident)
    s16x8 af[8];
    #pragma unroll
    for (int kk = 0; kk < 2; ++kk)
      #pragma unroll
      for (int fm = 0; fm < 4; ++fm) {
        int row = w * 64 + fm * 16 + ln15;
        af[kk * 4 + fm] = *reinterpret_cast<const s16x8*>(
            &A[(size_t)row * K + k0 + (kk * 4 + hi) * 8]);
      }
    // 2. write B(s+1) (loads issued one full step ago -> wait ~free)
    if (s + 1 < nsteps) writeB((s + 1) & 1);
    // 3. refill br with B(s+2); stays in flight across the barrier
    if (s + 2 < nsteps) loadB(kbeg + (s + 2) * 64);

    // 4. MFMA on buf s&1
    const short* bsrc = &Bs[s & 1][0];
    #pragma unroll
    for (int kk = 0; kk < 2; ++kk) {
      const int g = kk * 4 + hi;
      #pragma unroll
      for (int fn = 0; fn < 8; ++fn) {
        int row = fn * 16 + ln15;
        s16x8 bv = *reinterpret_cast<const s16x8*>(
            &bsrc[row * 64 + ((g ^ (row & 7)) * 8)]);
        #pragma unroll
        for (int fm = 0; fm < 4; ++fm)
          acc[fm][fn] = __builtin_amdgcn_mfma_f32_16x16x32_bf16(
              af[kk * 4 + fm], bv, acc[fm][fn], 0, 0, 0);
      }
    }
    __syncthreads();
  }

  #pragma unroll
  for (int fm = 0; fm < 4; ++fm)
    #pragma unroll
    for (int fn = 0; fn < 8; ++fn)
      #pragma unroll
      for (int j = 0; j < 4; ++j) {
        int row = w * 64 + fm * 16 + hi * 4 + j;
        int col = n0 + fn * 16 + ln15;
        part[((size_t)z * 512 + row) * N + col] = acc[fm][fn][j];
      }
}

// ---------------------------------------------------------------------------
// split-K reduce for mlp1: h3 = gelu(sum_ks part + b1), bf16, col<Nreal guard
// ---------------------------------------------------------------------------
__global__ __launch_bounds__(256) void reduce_mlp1_k(
    const float* __restrict__ part, const float* __restrict__ bias,
    short* __restrict__ h3, int N, int Nreal, int M, int ks)
{
  int col4 = (blockIdx.x * 256 + threadIdx.x) * 4;
  int row = blockIdx.y;
  if (col4 >= N) return;
  size_t base = (size_t)row * N + col4;
  size_t stride = (size_t)M * N;
  f32x4 s = *reinterpret_cast<const f32x4*>(part + base);
  for (int k = 1; k < ks; ++k)
    s += *reinterpret_cast<const f32x4*>(part + base + (size_t)k * stride);
  s16x4 o;
  #pragma unroll
  for (int j = 0; j < 4; ++j) {
    int c = col4 + j;
    float v = 0.f;
    if (c < Nreal) v = gelu_f(s[j] + bias[c]);
    o[j] = f2bf(v);
  }
  *reinterpret_cast<s16x4*>(h3 + base) = o;
}

// ---------------------------------------------------------------------------
// split-K reduce for mlp2: out = sum_ks part + b2 + x1 (f32)
// ---------------------------------------------------------------------------
__global__ __launch_bounds__(256) void reduce_mlp2_k(
    const float* __restrict__ part, const float* __restrict__ bias,
    const float* __restrict__ x1, float* __restrict__ out, int N, int M, int ks)
{
  int col4 = (blockIdx.x * 256 + threadIdx.x) * 4;
  int row = blockIdx.y;
  size_t base = (size_t)row * N + col4;
  size_t stride = (size_t)M * N;
  f32x4 s = *reinterpret_cast<const f32x4*>(part + base);
  for (int k = 1; k < ks; ++k)
    s += *reinterpret_cast<const f32x4*>(part + base + (size_t)k * stride);
  f32x4 b4 = *reinterpret_cast<const f32x4*>(bias + col4);
  f32x4 r4 = *reinterpret_cast<const f32x4*>(x1 + base);
  #pragma unroll
  for (int j = 0; j < 4; ++j) s[j] += b4[j] + r4[j];
  *reinterpret_cast<f32x4*>(out + base) = s;
}

// ---------------------------------------------------------------------------
// K4: fused tiny attention
// ---------------------------------------------------------------------------
__global__ __launch_bounds__(256) void attn_k(
    const short* __restrict__ qkv, const float* __restrict__ relb,
    const float* __restrict__ scale_p, short* __restrict__ av)
{
  __shared__ __align__(16) short qlds[64][136];
  __shared__ __align__(16) short klds[64][136];
  __shared__ __align__(16) short plds[64][72];
  __shared__ __align__(16) short vlds[128][72];
  __shared__ float rb[127];
  int t = threadIdx.x, lane = t & 63, w = t >> 6;
  int ln15 = lane & 15, hi = lane >> 4;
  int b = blockIdx.x;
  if (t < 127) rb[t] = relb[t];

  f32x4 sacc[4] = {};
  for (int kc = 0; kc < 4; ++kc) {
    #pragma unroll
    for (int i = 0; i < 4; ++i) {
      int e = (i*256 + t) * 8;
      int r = e >> 7, c = e & 127;
      size_t base = (size_t)(b*64 + r) * 1536 + kc*128 + c;
      *reinterpret_cast<i32x4*>(&qlds[r][c]) = *reinterpret_cast<const i32x4*>(&qkv[base]);
      *reinterpret_cast<i32x4*>(&klds[r][c]) = *reinterpret_cast<const i32x4*>(&qkv[base + 512]);
    }
    __syncthreads();
    #pragma unroll
    for (int kk = 0; kk < 128; kk += 32) {
      s16x8 aq = *reinterpret_cast<const s16x8*>(&qlds[16*w + ln15][kk + hi*8]);
      #pragma unroll
      for (int fn = 0; fn < 4; ++fn) {
        s16x8 bk = *reinterpret_cast<const s16x8*>(&klds[fn*16 + ln15][kk + hi*8]);
        sacc[fn] = __builtin_amdgcn_mfma_f32_16x16x32_bf16(aq, bk, sacc[fn], 0, 0, 0);
      }
    }
    __syncthreads();
  }

  float scale = scale_p[0];
  #pragma unroll
  for (int j = 0; j < 4; ++j) {
    int row = 16*w + hi*4 + j;
    float pv[4];
    float mx = -1e30f;
    #pragma unroll
    for (int fn = 0; fn < 4; ++fn) {
      int col = fn*16 + ln15;
      pv[fn] = sacc[fn][j] + rb[col - row + 63];
      mx = fmaxf(mx, pv[fn]);
    }
    #pragma unroll
    for (int d = 1; d < 16; d <<= 1) mx = fmaxf(mx, __shfl_xor(mx, d));
    float sum = 0.f;
    #pragma unroll
    for (int fn = 0; fn < 4; ++fn) { pv[fn] = __expf(pv[fn] - mx); sum += pv[fn]; }
    #pragma unroll
    for (int d = 1; d < 16; d <<= 1) sum += __shfl_xor(sum, d);
    float inv = scale / sum;
    #pragma unroll
    for (int fn = 0; fn < 4; ++fn) plds[row][fn*16 + ln15] = f2bf(pv[fn] * inv);
  }
  __syncthreads();

  for (int cc = 0; cc < 4; ++cc) {
    #pragma unroll
    for (int i = 0; i < 8; ++i) {
      int idx = i*256 + t;
      int s = idx >> 5, c4 = (idx & 31) * 4;
      s16x4 vw = *reinterpret_cast<const s16x4*>(
          &qkv[(size_t)(b*64 + s) * 1536 + 1024 + cc*128 + c4]);
      vlds[c4+0][s] = vw[0]; vlds[c4+1][s] = vw[1];
      vlds[c4+2][s] = vw[2]; vlds[c4+3][s] = vw[3];
    }
    __syncthreads();
    f32x4 pacc[8] = {};
    #pragma unroll
    for (int kk = 0; kk < 64; kk += 32) {
      s16x8 ap = *reinterpret_cast<const s16x8*>(&plds[16*w + ln15][kk + hi*8]);
      #pragma unroll
      for (int fn = 0; fn < 8; ++fn) {
        s16x8 bv = *reinterpret_cast<const s16x8*>(&vlds[fn*16 + ln15][kk + hi*8]);
        pacc[fn] = __builtin_amdgcn_mfma_f32_16x16x32_bf16(ap, bv, pacc[fn], 0, 0, 0);
      }
    }
    #pragma unroll
    for (int fn = 0; fn < 8; ++fn)
      #pragma unroll
      for (int j = 0; j < 4; ++j) {
        int row = b*64 + 16*w + hi*4 + j;
        int col = cc*128 + fn*16 + ln15;
        av[(size_t)row * 512 + col] = f2bf(pacc[fn][j]);
      }
    __syncthreads();
  }
}

// ---------------------------------------------------------------------------
// K5: SGU gate
// ---------------------------------------------------------------------------
__global__ __launch_bounds__(256) void gate_k(
    const float* __restrict__ u, const short* __restrict__ vbf,
    const float* __restrict__ a,
    const float* __restrict__ spg_g, const float* __restrict__ spg_b,
    const float* __restrict__ spw, const float* __restrict__ spb,
    const float* __restrict__ pog, const float* __restrict__ pob,
    short* __restrict__ outn)
{
  __shared__ __align__(16) short nvb[256][72];
  __shared__ __align__(16) short spwT[64][72];
  __shared__ float s_spg[64], s_spbl[64], s_spb[64];
  __shared__ float s_pog[256], s_pob[256];
  int t = threadIdx.x, lane = t & 63, w = t >> 6;
  int ln15 = lane & 15, hi = lane >> 4;
  int b = blockIdx.x;

  if (t < 64) { s_spg[t] = spg_g[t]; s_spbl[t] = spg_b[t]; s_spb[t] = spb[t]; }
  s_pog[t] = pog[t]; s_pob[t] = pob[t];
  #pragma unroll
  for (int i = 0; i < 16; ++i) {
    int idx = i*256 + t;
    int sr = idx >> 6, tc = idx & 63;
    spwT[tc][sr] = f2bf(spw[idx]);
  }

  float vvv[64];
  {
    int c = t;
    float s = 0.f, sq = 0.f;
    #pragma unroll
    for (int si = 0; si < 64; ++si) {
      float f = bf2f(vbf[(size_t)(b*64 + si) * 256 + c]);
      vvv[si] = f; s += f; sq += f*f;
    }
    float m = s * (1.f/64.f);
    float rstd = rsqrtf(sq * (1.f/64.f) - m*m + 1e-5f);
    __syncthreads();
    #pragma unroll
    for (int si = 0; si < 64; ++si)
      nvb[c][si] = f2bf((vvv[si]-m)*rstd*s_spg[si] + s_spbl[si]);
  }
  __syncthreads();

  f32x4 yacc[4][4] = {};
  #pragma unroll
  for (int kk = 0; kk < 64; kk += 32) {
    s16x8 af[4], bfr[4];
    #pragma unroll
    for (int fm = 0; fm < 4; ++fm)
      af[fm] = *reinterpret_cast<const s16x8*>(&nvb[64*w + fm*16 + ln15][kk + hi*8]);
    #pragma unroll
    for (int fn = 0; fn < 4; ++fn)
      bfr[fn] = *reinterpret_cast<const s16x8*>(&spwT[fn*16 + ln15][kk + hi*8]);
    #pragma unroll
    for (int fm = 0; fm < 4; ++fm)
      #pragma unroll
      for (int fn = 0; fn < 4; ++fn)
        yacc[fm][fn] = __builtin_amdgcn_mfma_f32_16x16x32_bf16(
            af[fm], bfr[fn], yacc[fm][fn], 0, 0, 0);
  }
  __syncthreads();

  short (*outl)[264] = reinterpret_cast<short(*)[264]>(&nvb[0][0]);
  #pragma unroll
  for (int fm = 0; fm < 4; ++fm) {
    #pragma unroll
    for (int fn = 0; fn < 4; ++fn) {
      int crow = 64*w + fm*16 + hi*4;
      int tcol = fn*16 + ln15;
      f32x4 u4 = *reinterpret_cast<const f32x4*>(&u[(size_t)(b*64 + tcol)*256 + crow]);
      f32x4 a4 = *reinterpret_cast<const f32x4*>(&a[(size_t)(b*64 + tcol)*256 + crow]);
      #pragma unroll
      for (int j = 0; j < 4; ++j) {
        float g = gelu_f(yacc[fm][fn][j] + s_spb[tcol]);
        float o = u4[j] * (g + a4[j]);
        outl[tcol][crow + j] = f2bf(o);
      }
    }
  }
  __syncthreads();

  #pragma unroll
  for (int ri = 0; ri < 16; ++ri) {
    int trow = w*16 + ri;
    int c = lane * 4;
    s16x4 raw = *reinterpret_cast<const s16x4*>(&outl[trow][c]);
    float f0 = bf2f(raw[0]), f1 = bf2f(raw[1]), f2 = bf2f(raw[2]), f3 = bf2f(raw[3]);
    float s  = f0+f1+f2+f3;
    float sq = f0*f0+f1*f1+f2*f2+f3*f3;
    s = waveSum(s); sq = waveSum(sq);
    float m = s * (1.f/256.f);
    float rstd = rsqrtf(sq * (1.f/256.f) - m*m + 1e-5f);
    s16x4 o;
    o[0] = f2bf((f0-m)*rstd*s_pog[c+0] + s_pob[c+0]);
    o[1] = f2bf((f1-m)*rstd*s_pog[c+1] + s_pob[c+1]);
    o[2] = f2bf((f2-m)*rstd*s_pog[c+2] + s_pob[c+2]);
    o[3] = f2bf((f3-m)*rstd*s_pog[c+3] + s_pob[c+3]);
    *reinterpret_cast<s16x4*>(&outn[(size_t)(b*64 + trow)*256 + c]) = o;
  }
}

// ---------------------------------------------------------------------------
extern "C" void kernel_launch(void* const* d_in, const int* in_sizes, int n_in,
                              void* d_out, int out_size, void* d_ws, size_t ws_size,
                              hipStream_t stream)
{
  const float* x          = (const float*)d_in[0];
  const float* qkv_ln_g   = (const float*)d_in[1];
  const float* qkv_ln_b   = (const float*)d_in[2];
  const float* qkv_w      = (const float*)d_in[3];
  const float* qkv_b      = (const float*)d_in[4];
  const float* attn_pw    = (const float*)d_in[5];
  const float* attn_pb    = (const float*)d_in[6];
  const float* attn_ln_g  = (const float*)d_in[7];
  const float* attn_ln_b  = (const float*)d_in[8];
  const float* rel_bias   = (const float*)d_in[9];
  const float* scale      = (const float*)d_in[10];
  const float* pin_ln_g   = (const float*)d_in[11];
  const float* pin_ln_b   = (const float*)d_in[12];
  const float* pin_w      = (const float*)d_in[13];
  const float* pin_b      = (const float*)d_in[14];
  const float* sp_ln_g    = (const float*)d_in[15];
  const float* sp_ln_b    = (const float*)d_in[16];
  const float* sp_w       = (const float*)d_in[17];
  const float* sp_b       = (const float*)d_in[18];
  const float* pout_ln_g  = (const float*)d_in[19];
  const float* pout_ln_b  = (const float*)d_in[20];
  const float* pout_w     = (const float*)d_in[21];
  const float* pout_b     = (const float*)d_in[22];
  const float* mlp_ln_g   = (const float*)d_in[23];
  const float* mlp_ln_b   = (const float*)d_in[24];
  const float* mlp_w1     = (const float*)d_in[25];
  const float* mlp_b1     = (const float*)d_in[26];
  const float* mlp_w2     = (const float*)d_in[27];
  const float* mlp_b2     = (const float*)d_in[28];

  char* ws = (char*)d_ws;
  short* lnq  = (short*)(ws + 0);            // 8.39 MB
  short* lnp  = (short*)(ws + 8388608);      // 8.39 MB
  short* qkvb = (short*)(ws + 16777216);     // 100.7 MB (dead after attn)
  short* avb  = (short*)(ws + 117440512);    // 33.6 MB
  float* projb= (float*)(ws + 16777216);     // alias qkv region
  float* ab   = (float*)(ws + 50331648);     // alias qkv region
  float* ub   = (float*)(ws + 83886080);     // alias qkv region
  short* vbfb = (short*)(ws + 117440512);    // alias av region
  short* outnb= (short*)(ws + 134217728);    // alias av region
  float* x1b  = (float*)(ws + 0);            // alias lnq/lnp region [0,16.8MB)
  short* lnxb = (short*)(ws + 150994944);    // 8.39 MB
  short* h3b  = (short*)(ws + 159383552);    // 9.31 MB (512 x 9088, pad zeroed)
  float* partb= (float*)(ws + 16777216);     // split-K partials (<=67 MB)

  ln_dual_k<<<8192, 256, 0, stream>>>(x, qkv_ln_g, qkv_ln_b, pin_ln_g, pin_ln_b, lnq, lnp);
  gemm_k<128,128,2,2,0><<<dim3(12,256), 256, 0, stream>>>(
      lnq, qkv_w, qkv_b, nullptr, qkvb, nullptr, 32768, 1536, 128, 1536, 128);
  attn_k<<<512, 256, 0, stream>>>(qkvb, rel_bias, scale, avb);
  gemm_k<128,128,2,2,1><<<dim3(2,256), 256, 0, stream>>>(
      avb, attn_pw, attn_pb, nullptr, projb, nullptr, 32768, 256, 512, 256, 512);
  ln256_k<<<8192, 256, 0, stream>>>(projb, attn_ln_g, attn_ln_b, ab);
  gemm_k<128,128,2,2,2><<<dim3(4,256), 256, 0, stream>>>(
      lnp, pin_w, pin_b, nullptr, ub, vbfb, 32768, 512, 128, 512, 128);
  gate_k<<<512, 256, 0, stream>>>(ub, vbfb, ab, sp_ln_g, sp_ln_b, sp_w, sp_b,
                                  pout_ln_g, pout_ln_b, outnb);
  gemm_k<128,128,2,2,3><<<dim3(1,256), 256, 0, stream>>>(
      outnb, pout_w, pout_b, x, x1b, nullptr, 32768, 128, 256, 128, 256);
  ln8192_k<<<512, 256, 0, stream>>>(x1b, mlp_ln_g, mlp_ln_b, lnxb);

  // mlp1: [512,8192] @ [8192,9011] (N padded 9088 = 71*128), split-K 3.
  // 213 blocks <= 256 CUs; chunks 43/43/42 steps.
  gemm_splitk6<<<213, 512, 0, stream>>>(
      lnxb, mlp_w1, partb, /*N=*/9088, /*K=*/8192, /*Kreal=*/8192,
      /*ldb=*/9011, /*kchunk=*/2752, /*ntiles=*/71);
  reduce_mlp1_k<<<dim3(9, 512), 256, 0, stream>>>(partb, mlp_b1, h3b, 9088, 9011, 512, 3);

  // mlp2: [512,9088] @ [9011,8192], split-K 4 (256 blocks; 36/36/36/34 steps).
  gemm_splitk6<<<256, 512, 0, stream>>>(
      h3b, mlp_w2, partb, /*N=*/8192, /*K=*/9088, /*Kreal=*/9011,
      /*ldb=*/8192, /*kchunk=*/2304, /*ntiles=*/64);
  reduce_mlp2_k<<<dim3(8, 512), 256, 0, stream>>>(partb, mlp_b2, x1b, (float*)d_out, 8192, 512, 4);
}

// Round 8
// 785.009 us; speedup vs baseline: 1.0561x; 1.0003x over previous
//
#include <hip/hip_runtime.h>
#include <hip/hip_bf16.h>
#include <math.h>

typedef float f32x4 __attribute__((ext_vector_type(4)));
typedef float f32x2 __attribute__((ext_vector_type(2)));
typedef short s16x8 __attribute__((ext_vector_type(8)));
typedef short s16x4 __attribute__((ext_vector_type(4)));
typedef int   i32x4 __attribute__((ext_vector_type(4)));

__device__ __forceinline__ short f2bf(float f) {
  __hip_bfloat16 h = __float2bfloat16(f);
  return __builtin_bit_cast(short, h);
}
__device__ __forceinline__ float bf2f(short s) {
  __hip_bfloat16 h = __builtin_bit_cast(__hip_bfloat16, s);
  return __bfloat162float(h);
}
__device__ __forceinline__ float gelu_f(float x) {
  return 0.5f * x * (1.f + erff(x * 0.70710678118654752440f));
}
__device__ __forceinline__ float waveSum(float v) {
  #pragma unroll
  for (int d = 32; d; d >>= 1) v += __shfl_xor(v, d);
  return v;
}
// Soft barrier: LDS-visibility only; does NOT drain vmcnt, so global-load
// prefetches stay in flight across it (T3/T4 idiom; __syncthreads would
// emit s_waitcnt vmcnt(0) and kill the pipeline).
__device__ __forceinline__ void softBarrier() {
  asm volatile("s_waitcnt lgkmcnt(0)" ::: "memory");
  __builtin_amdgcn_s_barrier();
  asm volatile("" ::: "memory");
}

// ---------------------------------------------------------------------------
// K1: dual LayerNorm over D=128 (qkv_ln and pin_ln) -> bf16 A-matrices
// ---------------------------------------------------------------------------
__global__ __launch_bounds__(256) void ln_dual_k(
    const float* __restrict__ x,
    const float* __restrict__ qg, const float* __restrict__ qb,
    const float* __restrict__ pg, const float* __restrict__ pb,
    short* __restrict__ lnq, short* __restrict__ lnp)
{
  int w = threadIdx.x >> 6, lane = threadIdx.x & 63;
  size_t row = (size_t)blockIdx.x * 4 + w;
  f32x2 v = reinterpret_cast<const f32x2*>(x + row * 128)[lane];
  float s  = v[0] + v[1];
  float sq = v[0]*v[0] + v[1]*v[1];
  s = waveSum(s); sq = waveSum(sq);
  float m = s * (1.f/128.f);
  float rstd = rsqrtf(sq * (1.f/128.f) - m*m + 1e-5f);
  int c = lane * 2;
  float a0 = (v[0]-m)*rstd, a1 = (v[1]-m)*rstd;
  unsigned q0 = (unsigned short)f2bf(a0*qg[c] + qb[c]);
  unsigned q1 = (unsigned short)f2bf(a1*qg[c+1] + qb[c+1]);
  unsigned p0 = (unsigned short)f2bf(a0*pg[c] + pb[c]);
  unsigned p1 = (unsigned short)f2bf(a1*pg[c+1] + pb[c+1]);
  ((unsigned*)lnq)[row*64 + lane] = q0 | (q1 << 16);
  ((unsigned*)lnp)[row*64 + lane] = p0 | (p1 << 16);
}

// ---------------------------------------------------------------------------
// K2: LayerNorm over 256 (attn_ln), fp32 in/out
// ---------------------------------------------------------------------------
__global__ __launch_bounds__(256) void ln256_k(
    const float* __restrict__ in,
    const float* __restrict__ g, const float* __restrict__ bb,
    float* __restrict__ out)
{
  int w = threadIdx.x >> 6, lane = threadIdx.x & 63;
  size_t row = (size_t)blockIdx.x * 4 + w;
  f32x4 v = reinterpret_cast<const f32x4*>(in + row * 256)[lane];
  float s  = v[0]+v[1]+v[2]+v[3];
  float sq = v[0]*v[0]+v[1]*v[1]+v[2]*v[2]+v[3]*v[3];
  s = waveSum(s); sq = waveSum(sq);
  float m = s * (1.f/256.f);
  float rstd = rsqrtf(sq * (1.f/256.f) - m*m + 1e-5f);
  f32x4 g4 = reinterpret_cast<const f32x4*>(g)[lane];
  f32x4 b4 = reinterpret_cast<const f32x4*>(bb)[lane];
  f32x4 o;
  #pragma unroll
  for (int k = 0; k < 4; ++k) o[k] = (v[k]-m)*rstd*g4[k] + b4[k];
  reinterpret_cast<f32x4*>(out + row * 256)[lane] = o;
}

// ---------------------------------------------------------------------------
// K3: LayerNorm over 8192 (mlp_ln) -> bf16
// ---------------------------------------------------------------------------
__global__ __launch_bounds__(256) void ln8192_k(
    const float* __restrict__ x1,
    const float* __restrict__ g, const float* __restrict__ bb,
    short* __restrict__ lnx)
{
  __shared__ float red[8];
  int t = threadIdx.x, w = t >> 6, lane = t & 63;
  int b = blockIdx.x;
  const f32x4* xr = reinterpret_cast<const f32x4*>(x1 + (size_t)b * 8192);
  f32x4 vals[8];
  float s = 0.f, sq = 0.f;
  #pragma unroll
  for (int i = 0; i < 8; ++i) {
    f32x4 v = xr[t + i*256];
    vals[i] = v;
    s  += v[0]+v[1]+v[2]+v[3];
    sq += v[0]*v[0]+v[1]*v[1]+v[2]*v[2]+v[3]*v[3];
  }
  s = waveSum(s); sq = waveSum(sq);
  if (lane == 0) { red[w] = s; red[4+w] = sq; }
  __syncthreads();
  s  = red[0]+red[1]+red[2]+red[3];
  sq = red[4]+red[5]+red[6]+red[7];
  float m = s * (1.f/8192.f);
  float rstd = rsqrtf(sq * (1.f/8192.f) - m*m + 1e-5f);
  #pragma unroll
  for (int i = 0; i < 8; ++i) {
    int idx = (t + i*256) * 4;
    f32x4 g4 = reinterpret_cast<const f32x4*>(g)[t + i*256];
    f32x4 b4 = reinterpret_cast<const f32x4*>(bb)[t + i*256];
    s16x4 o;
    #pragma unroll
    for (int k = 0; k < 4; ++k) o[k] = f2bf((vals[i][k]-m)*rstd*g4[k] + b4[k]);
    *reinterpret_cast<s16x4*>(&lnx[(size_t)b*8192 + idx]) = o;
  }
}

// ---------------------------------------------------------------------------
// Generic bf16-MFMA GEMM for the small GEMMs.
// EPI: 0 = bf16 out (+bias); 1 = f32 out (+bias); 2 = gelu split u/v (pin);
//      3 = f32 out (+bias +res)
// ---------------------------------------------------------------------------
template<int BM, int BN, int WM, int WN, int EPI>
__global__ __launch_bounds__(256) void gemm_k(
    const short* __restrict__ A, const float* __restrict__ Bw,
    const float* __restrict__ bias, const float* __restrict__ res,
    void* __restrict__ O0, void* __restrict__ O1,
    int M, int N, int K, int Nreal, int Kreal)
{
  constexpr int BK = 64;
  __shared__ __align__(16) short As[BM][BK + 8];
  __shared__ __align__(16) short Bs[BN][BK + 8];
  const int t = threadIdx.x;
  const int lane = t & 63;
  const int w = t >> 6;
  const int wm = w / WN, wn = w % WN;
  const int ln15 = lane & 15, hi = lane >> 4;
  const int m0 = blockIdx.y * BM;
  const int n0 = blockIdx.x * BN;

  f32x4 acc[4][4] = {};

  for (int k0 = 0; k0 < K; k0 += BK) {
    #pragma unroll
    for (int i = 0; i < (BM*BK)/(256*8); ++i) {
      int e = (i*256 + t) * 8;
      int r = e / BK, c = e % BK;
      *reinterpret_cast<i32x4*>(&As[r][c]) =
          *reinterpret_cast<const i32x4*>(&A[(size_t)(m0 + r) * K + k0 + c]);
    }
    #pragma unroll
    for (int i = 0; i < (BK*BN)/256; ++i) {
      int idx = i*256 + t;
      int n = idx % BN, k = idx / BN;
      int gk = k0 + k, gn = n0 + n;
      float v = (gk < Kreal && gn < Nreal) ? Bw[(size_t)gk * Nreal + gn] : 0.f;
      Bs[n][k] = f2bf(v);
    }
    __syncthreads();
    #pragma unroll
    for (int kk = 0; kk < BK; kk += 32) {
      s16x8 af[4], bfr[4];
      #pragma unroll
      for (int fm = 0; fm < 4; ++fm)
        af[fm] = *reinterpret_cast<const s16x8*>(&As[wm*64 + fm*16 + ln15][kk + hi*8]);
      #pragma unroll
      for (int fn = 0; fn < 4; ++fn)
        bfr[fn] = *reinterpret_cast<const s16x8*>(&Bs[wn*64 + fn*16 + ln15][kk + hi*8]);
      #pragma unroll
      for (int fm = 0; fm < 4; ++fm)
        #pragma unroll
        for (int fn = 0; fn < 4; ++fn)
          acc[fm][fn] = __builtin_amdgcn_mfma_f32_16x16x32_bf16(
              af[fm], bfr[fn], acc[fm][fn], 0, 0, 0);
    }
    __syncthreads();
  }

  #pragma unroll
  for (int fm = 0; fm < 4; ++fm) {
    #pragma unroll
    for (int fn = 0; fn < 4; ++fn) {
      #pragma unroll
      for (int j = 0; j < 4; ++j) {
        int row = m0 + wm*64 + fm*16 + hi*4 + j;
        int col = n0 + wn*64 + fn*16 + ln15;
        float v = acc[fm][fn][j];
        if constexpr (EPI == 0) {
          v += bias[col];
          ((short*)O0)[(size_t)row * N + col] = f2bf(v);
        } else if constexpr (EPI == 1) {
          v += bias[col];
          ((float*)O0)[(size_t)row * N + col] = v;
        } else if constexpr (EPI == 2) {
          v = gelu_f(v + bias[col]);
          if (col < 256) ((float*)O0)[(size_t)row * 256 + col] = v;
          else ((short*)O1)[(size_t)row * 256 + (col - 256)] = f2bf(v);
        } else { // 3
          v += bias[col] + res[(size_t)row * N + col];
          ((float*)O0)[(size_t)row * N + col] = v;
        }
      }
    }
  }
}

// ---------------------------------------------------------------------------
// Split-K GEMM v7 for the fat MLP GEMMs.
// Identical tiling/pipeline to v6 (BM=512, BN=128, BK=64, 8 waves, A direct
// global->VGPR, B double-buffered LDS w/ XOR swizzle, write-early/load-late).
// ONE change: the per-step barrier is a SOFT barrier (lgkmcnt(0) + raw
// s_barrier). __syncthreads() emits s_waitcnt vmcnt(0) which force-drained
// the B(s+2) prefetch every step (R7 null result). With the soft barrier the
// compiler's own COUNTED vmcnt waits remain: writeB waits only for B(s+1)
// (A in flight), MFMA waits only for A(s) (B(s+2) in flight across the
// barrier into the next step).
// ---------------------------------------------------------------------------
__global__ __launch_bounds__(512, 2) void gemm_splitk7(
    const short* __restrict__ A, const float* __restrict__ Bw,
    float* __restrict__ part,
    int N, int K, int Kreal, int ldb, int kchunk, int ntiles)
{
  __shared__ __align__(16) short Bs[2][128 * 64];  // 2 x 16 KB
  const int t = threadIdx.x, lane = t & 63, w = t >> 6;
  const int ln15 = lane & 15, hi = lane >> 4;
  const int nt = blockIdx.x % ntiles, z = blockIdx.x / ntiles;
  const int n0 = nt * 128;
  const int kbeg = z * kchunk;
  const int kend = (kbeg + kchunk < K) ? (kbeg + kchunk) : K;
  const int nsteps = (kend - kbeg) >> 6;

  const int bn = t & 127;
  const int bg0 = (t >> 7) * 2;
  const bool bok = (n0 + bn) < ldb;
  const int bsw = bn & 7;                    // XOR swizzle key

  float br[16];
  auto loadB = [&](int k0) {
    const float* bp = Bw + (size_t)(k0 + bg0 * 8) * ldb + n0 + bn;
    #pragma unroll
    for (int m = 0; m < 16; ++m) {
      int gk = k0 + bg0 * 8 + m;
      br[m] = (bok && gk < Kreal) ? bp[(size_t)m * ldb] : 0.f;
    }
  };
  auto writeB = [&](int buf) {
    s16x8 v0, v1;
    #pragma unroll
    for (int m = 0; m < 8; ++m) { v0[m] = f2bf(br[m]); v1[m] = f2bf(br[8 + m]); }
    short* dst = &Bs[buf][bn * 64];
    *reinterpret_cast<s16x8*>(dst + ((bg0    ) ^ bsw) * 8) = v0;
    *reinterpret_cast<s16x8*>(dst + ((bg0 + 1) ^ bsw) * 8) = v1;
  };

  f32x4 acc[4][8] = {};

  // prologue: buf0 <- B(step 0); br <- B(step 1) stays in flight
  loadB(kbeg);
  writeB(0);
  if (nsteps > 1) loadB(kbeg + 64);
  softBarrier();

  for (int s = 0; s < nsteps; ++s) {
    const int k0 = kbeg + s * 64;
    // 1. A fragments for THIS step (L2-resident)
    s16x8 af[8];
    #pragma unroll
    for (int kk = 0; kk < 2; ++kk)
      #pragma unroll
      for (int fm = 0; fm < 4; ++fm) {
        int row = w * 64 + fm * 16 + ln15;
        af[kk * 4 + fm] = *reinterpret_cast<const s16x8*>(
            &A[(size_t)row * K + k0 + (kk * 4 + hi) * 8]);
      }
    // 2. write B(s+1): its loads were issued a full step ago (counted wait)
    if (s + 1 < nsteps) writeB((s + 1) & 1);
    // 3. refill br with B(s+2); stays in flight across the SOFT barrier
    if (s + 2 < nsteps) loadB(kbeg + (s + 2) * 64);

    // 4. MFMA on buf s&1 (waits only for A(s))
    const short* bsrc = &Bs[s & 1][0];
    #pragma unroll
    for (int kk = 0; kk < 2; ++kk) {
      const int g = kk * 4 + hi;
      #pragma unroll
      for (int fn = 0; fn < 8; ++fn) {
        int row = fn * 16 + ln15;
        s16x8 bv = *reinterpret_cast<const s16x8*>(
            &bsrc[row * 64 + ((g ^ (row & 7)) * 8)]);
        #pragma unroll
        for (int fm = 0; fm < 4; ++fm)
          acc[fm][fn] = __builtin_amdgcn_mfma_f32_16x16x32_bf16(
              af[kk * 4 + fm], bv, acc[fm][fn], 0, 0, 0);
      }
    }
    softBarrier();
  }

  #pragma unroll
  for (int fm = 0; fm < 4; ++fm)
    #pragma unroll
    for (int fn = 0; fn < 8; ++fn)
      #pragma unroll
      for (int j = 0; j < 4; ++j) {
        int row = w * 64 + fm * 16 + hi * 4 + j;
        int col = n0 + fn * 16 + ln15;
        part[((size_t)z * 512 + row) * N + col] = acc[fm][fn][j];
      }
}

// ---------------------------------------------------------------------------
// split-K reduce for mlp1: h3 = gelu(sum_ks part + b1), bf16, col<Nreal guard
// ---------------------------------------------------------------------------
__global__ __launch_bounds__(256) void reduce_mlp1_k(
    const float* __restrict__ part, const float* __restrict__ bias,
    short* __restrict__ h3, int N, int Nreal, int M, int ks)
{
  int col4 = (blockIdx.x * 256 + threadIdx.x) * 4;
  int row = blockIdx.y;
  if (col4 >= N) return;
  size_t base = (size_t)row * N + col4;
  size_t stride = (size_t)M * N;
  f32x4 s = *reinterpret_cast<const f32x4*>(part + base);
  for (int k = 1; k < ks; ++k)
    s += *reinterpret_cast<const f32x4*>(part + base + (size_t)k * stride);
  s16x4 o;
  #pragma unroll
  for (int j = 0; j < 4; ++j) {
    int c = col4 + j;
    float v = 0.f;
    if (c < Nreal) v = gelu_f(s[j] + bias[c]);
    o[j] = f2bf(v);
  }
  *reinterpret_cast<s16x4*>(h3 + base) = o;
}

// ---------------------------------------------------------------------------
// split-K reduce for mlp2: out = sum_ks part + b2 + x1 (f32)
// ---------------------------------------------------------------------------
__global__ __launch_bounds__(256) void reduce_mlp2_k(
    const float* __restrict__ part, const float* __restrict__ bias,
    const float* __restrict__ x1, float* __restrict__ out, int N, int M, int ks)
{
  int col4 = (blockIdx.x * 256 + threadIdx.x) * 4;
  int row = blockIdx.y;
  size_t base = (size_t)row * N + col4;
  size_t stride = (size_t)M * N;
  f32x4 s = *reinterpret_cast<const f32x4*>(part + base);
  for (int k = 1; k < ks; ++k)
    s += *reinterpret_cast<const f32x4*>(part + base + (size_t)k * stride);
  f32x4 b4 = *reinterpret_cast<const f32x4*>(bias + col4);
  f32x4 r4 = *reinterpret_cast<const f32x4*>(x1 + base);
  #pragma unroll
  for (int j = 0; j < 4; ++j) s[j] += b4[j] + r4[j];
  *reinterpret_cast<f32x4*>(out + base) = s;
}

// ---------------------------------------------------------------------------
// K4: fused tiny attention
// ---------------------------------------------------------------------------
__global__ __launch_bounds__(256) void attn_k(
    const short* __restrict__ qkv, const float* __restrict__ relb,
    const float* __restrict__ scale_p, short* __restrict__ av)
{
  __shared__ __align__(16) short qlds[64][136];
  __shared__ __align__(16) short klds[64][136];
  __shared__ __align__(16) short plds[64][72];
  __shared__ __align__(16) short vlds[128][72];
  __shared__ float rb[127];
  int t = threadIdx.x, lane = t & 63, w = t >> 6;
  int ln15 = lane & 15, hi = lane >> 4;
  int b = blockIdx.x;
  if (t < 127) rb[t] = relb[t];

  f32x4 sacc[4] = {};
  for (int kc = 0; kc < 4; ++kc) {
    #pragma unroll
    for (int i = 0; i < 4; ++i) {
      int e = (i*256 + t) * 8;
      int r = e >> 7, c = e & 127;
      size_t base = (size_t)(b*64 + r) * 1536 + kc*128 + c;
      *reinterpret_cast<i32x4*>(&qlds[r][c]) = *reinterpret_cast<const i32x4*>(&qkv[base]);
      *reinterpret_cast<i32x4*>(&klds[r][c]) = *reinterpret_cast<const i32x4*>(&qkv[base + 512]);
    }
    __syncthreads();
    #pragma unroll
    for (int kk = 0; kk < 128; kk += 32) {
      s16x8 aq = *reinterpret_cast<const s16x8*>(&qlds[16*w + ln15][kk + hi*8]);
      #pragma unroll
      for (int fn = 0; fn < 4; ++fn) {
        s16x8 bk = *reinterpret_cast<const s16x8*>(&klds[fn*16 + ln15][kk + hi*8]);
        sacc[fn] = __builtin_amdgcn_mfma_f32_16x16x32_bf16(aq, bk, sacc[fn], 0, 0, 0);
      }
    }
    __syncthreads();
  }

  float scale = scale_p[0];
  #pragma unroll
  for (int j = 0; j < 4; ++j) {
    int row = 16*w + hi*4 + j;
    float pv[4];
    float mx = -1e30f;
    #pragma unroll
    for (int fn = 0; fn < 4; ++fn) {
      int col = fn*16 + ln15;
      pv[fn] = sacc[fn][j] + rb[col - row + 63];
      mx = fmaxf(mx, pv[fn]);
    }
    #pragma unroll
    for (int d = 1; d < 16; d <<= 1) mx = fmaxf(mx, __shfl_xor(mx, d));
    float sum = 0.f;
    #pragma unroll
    for (int fn = 0; fn < 4; ++fn) { pv[fn] = __expf(pv[fn] - mx); sum += pv[fn]; }
    #pragma unroll
    for (int d = 1; d < 16; d <<= 1) sum += __shfl_xor(sum, d);
    float inv = scale / sum;
    #pragma unroll
    for (int fn = 0; fn < 4; ++fn) plds[row][fn*16 + ln15] = f2bf(pv[fn] * inv);
  }
  __syncthreads();

  for (int cc = 0; cc < 4; ++cc) {
    #pragma unroll
    for (int i = 0; i < 8; ++i) {
      int idx = i*256 + t;
      int s = idx >> 5, c4 = (idx & 31) * 4;
      s16x4 vw = *reinterpret_cast<const s16x4*>(
          &qkv[(size_t)(b*64 + s) * 1536 + 1024 + cc*128 + c4]);
      vlds[c4+0][s] = vw[0]; vlds[c4+1][s] = vw[1];
      vlds[c4+2][s] = vw[2]; vlds[c4+3][s] = vw[3];
    }
    __syncthreads();
    f32x4 pacc[8] = {};
    #pragma unroll
    for (int kk = 0; kk < 64; kk += 32) {
      s16x8 ap = *reinterpret_cast<const s16x8*>(&plds[16*w + ln15][kk + hi*8]);
      #pragma unroll
      for (int fn = 0; fn < 8; ++fn) {
        s16x8 bv = *reinterpret_cast<const s16x8*>(&vlds[fn*16 + ln15][kk + hi*8]);
        pacc[fn] = __builtin_amdgcn_mfma_f32_16x16x32_bf16(ap, bv, pacc[fn], 0, 0, 0);
      }
    }
    #pragma unroll
    for (int fn = 0; fn < 8; ++fn)
      #pragma unroll
      for (int j = 0; j < 4; ++j) {
        int row = b*64 + 16*w + hi*4 + j;
        int col = cc*128 + fn*16 + ln15;
        av[(size_t)row * 512 + col] = f2bf(pacc[fn][j]);
      }
    __syncthreads();
  }
}

// ---------------------------------------------------------------------------
// K5: SGU gate
// ---------------------------------------------------------------------------
__global__ __launch_bounds__(256) void gate_k(
    const float* __restrict__ u, const short* __restrict__ vbf,
    const float* __restrict__ a,
    const float* __restrict__ spg_g, const float* __restrict__ spg_b,
    const float* __restrict__ spw, const float* __restrict__ spb,
    const float* __restrict__ pog, const float* __restrict__ pob,
    short* __restrict__ outn)
{
  __shared__ __align__(16) short nvb[256][72];
  __shared__ __align__(16) short spwT[64][72];
  __shared__ float s_spg[64], s_spbl[64], s_spb[64];
  __shared__ float s_pog[256], s_pob[256];
  int t = threadIdx.x, lane = t & 63, w = t >> 6;
  int ln15 = lane & 15, hi = lane >> 4;
  int b = blockIdx.x;

  if (t < 64) { s_spg[t] = spg_g[t]; s_spbl[t] = spg_b[t]; s_spb[t] = spb[t]; }
  s_pog[t] = pog[t]; s_pob[t] = pob[t];
  #pragma unroll
  for (int i = 0; i < 16; ++i) {
    int idx = i*256 + t;
    int sr = idx >> 6, tc = idx & 63;
    spwT[tc][sr] = f2bf(spw[idx]);
  }

  float vvv[64];
  {
    int c = t;
    float s = 0.f, sq = 0.f;
    #pragma unroll
    for (int si = 0; si < 64; ++si) {
      float f = bf2f(vbf[(size_t)(b*64 + si) * 256 + c]);
      vvv[si] = f; s += f; sq += f*f;
    }
    float m = s * (1.f/64.f);
    float rstd = rsqrtf(sq * (1.f/64.f) - m*m + 1e-5f);
    __syncthreads();
    #pragma unroll
    for (int si = 0; si < 64; ++si)
      nvb[c][si] = f2bf((vvv[si]-m)*rstd*s_spg[si] + s_spbl[si]);
  }
  __syncthreads();

  f32x4 yacc[4][4] = {};
  #pragma unroll
  for (int kk = 0; kk < 64; kk += 32) {
    s16x8 af[4], bfr[4];
    #pragma unroll
    for (int fm = 0; fm < 4; ++fm)
      af[fm] = *reinterpret_cast<const s16x8*>(&nvb[64*w + fm*16 + ln15][kk + hi*8]);
    #pragma unroll
    for (int fn = 0; fn < 4; ++fn)
      bfr[fn] = *reinterpret_cast<const s16x8*>(&spwT[fn*16 + ln15][kk + hi*8]);
    #pragma unroll
    for (int fm = 0; fm < 4; ++fm)
      #pragma unroll
      for (int fn = 0; fn < 4; ++fn)
        yacc[fm][fn] = __builtin_amdgcn_mfma_f32_16x16x32_bf16(
            af[fm], bfr[fn], yacc[fm][fn], 0, 0, 0);
  }
  __syncthreads();

  short (*outl)[264] = reinterpret_cast<short(*)[264]>(&nvb[0][0]);
  #pragma unroll
  for (int fm = 0; fm < 4; ++fm) {
    #pragma unroll
    for (int fn = 0; fn < 4; ++fn) {
      int crow = 64*w + fm*16 + hi*4;
      int tcol = fn*16 + ln15;
      f32x4 u4 = *reinterpret_cast<const f32x4*>(&u[(size_t)(b*64 + tcol)*256 + crow]);
      f32x4 a4 = *reinterpret_cast<const f32x4*>(&a[(size_t)(b*64 + tcol)*256 + crow]);
      #pragma unroll
      for (int j = 0; j < 4; ++j) {
        float g = gelu_f(yacc[fm][fn][j] + s_spb[tcol]);
        float o = u4[j] * (g + a4[j]);
        outl[tcol][crow + j] = f2bf(o);
      }
    }
  }
  __syncthreads();

  #pragma unroll
  for (int ri = 0; ri < 16; ++ri) {
    int trow = w*16 + ri;
    int c = lane * 4;
    s16x4 raw = *reinterpret_cast<const s16x4*>(&outl[trow][c]);
    float f0 = bf2f(raw[0]), f1 = bf2f(raw[1]), f2 = bf2f(raw[2]), f3 = bf2f(raw[3]);
    float s  = f0+f1+f2+f3;
    float sq = f0*f0+f1*f1+f2*f2+f3*f3;
    s = waveSum(s); sq = waveSum(sq);
    float m = s * (1.f/256.f);
    float rstd = rsqrtf(sq * (1.f/256.f) - m*m + 1e-5f);
    s16x4 o;
    o[0] = f2bf((f0-m)*rstd*s_pog[c+0] + s_pob[c+0]);
    o[1] = f2bf((f1-m)*rstd*s_pog[c+1] + s_pob[c+1]);
    o[2] = f2bf((f2-m)*rstd*s_pog[c+2] + s_pob[c+2]);
    o[3] = f2bf((f3-m)*rstd*s_pog[c+3] + s_pob[c+3]);
    *reinterpret_cast<s16x4*>(&outn[(size_t)(b*64 + trow)*256 + c]) = o;
  }
}

// ---------------------------------------------------------------------------
extern "C" void kernel_launch(void* const* d_in, const int* in_sizes, int n_in,
                              void* d_out, int out_size, void* d_ws, size_t ws_size,
                              hipStream_t stream)
{
  const float* x          = (const float*)d_in[0];
  const float* qkv_ln_g   = (const float*)d_in[1];
  const float* qkv_ln_b   = (const float*)d_in[2];
  const float* qkv_w      = (const float*)d_in[3];
  const float* qkv_b      = (const float*)d_in[4];
  const float* attn_pw    = (const float*)d_in[5];
  const float* attn_pb    = (const float*)d_in[6];
  const float* attn_ln_g  = (const float*)d_in[7];
  const float* attn_ln_b  = (const float*)d_in[8];
  const float* rel_bias   = (const float*)d_in[9];
  const float* scale      = (const float*)d_in[10];
  const float* pin_ln_g   = (const float*)d_in[11];
  const float* pin_ln_b   = (const float*)d_in[12];
  const float* pin_w      = (const float*)d_in[13];
  const float* pin_b      = (const float*)d_in[14];
  const float* sp_ln_g    = (const float*)d_in[15];
  const float* sp_ln_b    = (const float*)d_in[16];
  const float* sp_w       = (const float*)d_in[17];
  const float* sp_b       = (const float*)d_in[18];
  const float* pout_ln_g  = (const float*)d_in[19];
  const float* pout_ln_b  = (const float*)d_in[20];
  const float* pout_w     = (const float*)d_in[21];
  const float* pout_b     = (const float*)d_in[22];
  const float* mlp_ln_g   = (const float*)d_in[23];
  const float* mlp_ln_b   = (const float*)d_in[24];
  const float* mlp_w1     = (const float*)d_in[25];
  const float* mlp_b1     = (const float*)d_in[26];
  const float* mlp_w2     = (const float*)d_in[27];
  const float* mlp_b2     = (const float*)d_in[28];

  char* ws = (char*)d_ws;
  short* lnq  = (short*)(ws + 0);            // 8.39 MB
  short* lnp  = (short*)(ws + 8388608);      // 8.39 MB
  short* qkvb = (short*)(ws + 16777216);     // 100.7 MB (dead after attn)
  short* avb  = (short*)(ws + 117440512);    // 33.6 MB
  float* projb= (float*)(ws + 16777216);     // alias qkv region
  float* ab   = (float*)(ws + 50331648);     // alias qkv region
  float* ub   = (float*)(ws + 83886080);     // alias qkv region
  short* vbfb = (short*)(ws + 117440512);    // alias av region
  short* outnb= (short*)(ws + 134217728);    // alias av region
  float* x1b  = (float*)(ws + 0);            // alias lnq/lnp region [0,16.8MB)
  short* lnxb = (short*)(ws + 150994944);    // 8.39 MB
  short* h3b  = (short*)(ws + 159383552);    // 9.31 MB (512 x 9088, pad zeroed)
  float* partb= (float*)(ws + 16777216);     // split-K partials (<=67 MB)

  ln_dual_k<<<8192, 256, 0, stream>>>(x, qkv_ln_g, qkv_ln_b, pin_ln_g, pin_ln_b, lnq, lnp);
  gemm_k<128,128,2,2,0><<<dim3(12,256), 256, 0, stream>>>(
      lnq, qkv_w, qkv_b, nullptr, qkvb, nullptr, 32768, 1536, 128, 1536, 128);
  attn_k<<<512, 256, 0, stream>>>(qkvb, rel_bias, scale, avb);
  gemm_k<128,128,2,2,1><<<dim3(2,256), 256, 0, stream>>>(
      avb, attn_pw, attn_pb, nullptr, projb, nullptr, 32768, 256, 512, 256, 512);
  ln256_k<<<8192, 256, 0, stream>>>(projb, attn_ln_g, attn_ln_b, ab);
  gemm_k<128,128,2,2,2><<<dim3(4,256), 256, 0, stream>>>(
      lnp, pin_w, pin_b, nullptr, ub, vbfb, 32768, 512, 128, 512, 128);
  gate_k<<<512, 256, 0, stream>>>(ub, vbfb, ab, sp_ln_g, sp_ln_b, sp_w, sp_b,
                                  pout_ln_g, pout_ln_b, outnb);
  gemm_k<128,128,2,2,3><<<dim3(1,256), 256, 0, stream>>>(
      outnb, pout_w, pout_b, x, x1b, nullptr, 32768, 128, 256, 128, 256);
  ln8192_k<<<512, 256, 0, stream>>>(x1b, mlp_ln_g, mlp_ln_b, lnxb);

  // mlp1: [512,8192] @ [8192,9011] (N padded 9088 = 71*128), split-K 3.
  // 213 blocks <= 256 CUs; chunks 43/43/42 steps.
  gemm_splitk7<<<213, 512, 0, stream>>>(
      lnxb, mlp_w1, partb, /*N=*/9088, /*K=*/8192, /*Kreal=*/8192,
      /*ldb=*/9011, /*kchunk=*/2752, /*ntiles=*/71);
  reduce_mlp1_k<<<dim3(9, 512), 256, 0, stream>>>(partb, mlp_b1, h3b, 9088, 9011, 512, 3);

  // mlp2: [512,9088] @ [9011,8192], split-K 4 (256 blocks; 36/36/36/34 steps).
  gemm_splitk7<<<256, 512, 0, stream>>>(
      h3b, mlp_w2, partb, /*N=*/8192, /*K=*/9088, /*Kreal=*/9011,
      /*ldb=*/8192, /*kchunk=*/2304, /*ntiles=*/64);
  reduce_mlp2_k<<<dim3(8, 512), 256, 0, stream>>>(partb, mlp_b2, x1b, (float*)d_out, 8192, 512, 4);
}